// Round 3
// baseline (5874.967 us; speedup 1.0000x reference)
//
#include <hip/hip_runtime.h>
#include <math.h>
#include <stdint.h>

#define VOCAB 2048
#define EMB   512
#define HID   1024
#define TX    256
#define BATCH 64
#define NBLK  256

typedef __attribute__((ext_vector_type(8))) short bf16x8;
typedef __attribute__((ext_vector_type(4))) float f32x4;
typedef unsigned int u32;
typedef unsigned short u16;
typedef __attribute__((ext_vector_type(4))) u32 u32x4;

// ---------------- ws byte offsets ----------------
// flags0/1 : [256 t][256 blk] int   (memset 0 each launch)
// h0P      : 257 slabs of [128 kblk][64 b][8] bf16  (slab t+1 = h0 at step t)
// h1P      : 257 slabs, same layout (slab 0 zeroed)
// xP       : [TX][64 kblk][64 b][8] bf16
#define OFF_FLAGS0 0u
#define OFF_FLAGS1 262144u
#define OFF_H0     524288u
#define OFF_H1     34209792u
#define OFF_XP     67895296u
#define SLAB_U16   65536u
#define SLAB_V4    8192u

__device__ __forceinline__ u16 f2bf(float x){
  u32 v = __float_as_uint(x);
  v += 0x7fffu + ((v >> 16) & 1u);          // RNE
  return (u16)(v >> 16);
}
__device__ __forceinline__ u32 pack2(float a, float b){
  return (u32)f2bf(a) | ((u32)f2bf(b) << 16);
}
__device__ __forceinline__ float bf2f(u16 h){ return __uint_as_float(((u32)h) << 16); }
__device__ __forceinline__ float sigm(float x){ return 1.f/(1.f+__expf(-x)); }
__device__ __forceinline__ float tanh_(float x){
  float e = __expf(2.f*fabsf(x));           // overflow-safe
  return copysignf(1.f - 2.f/(e+1.f), x);
}

// ---------------------------------------------------------------------------
__global__ __launch_bounds__(256) void embed_pack(
    const int* __restrict__ x, const float* __restrict__ emb, u32x4* __restrict__ xP)
{
  int flat = blockIdx.x*256 + threadIdx.x;   // t*4096 + kblk*64 + b
  int b    = flat & 63;
  int kblk = (flat >> 6) & 63;
  int t    = flat >> 12;
  int idx  = x[b*TX + t];
  const float* src = emb + (size_t)idx*EMB + kblk*8;
  u32x4 o;
  o.x = pack2(src[0], src[1]);
  o.y = pack2(src[2], src[3]);
  o.z = pack2(src[4], src[5]);
  o.w = pack2(src[6], src[7]);
  xP[flat] = o;
}

// ---------------------------------------------------------------------------
// Persistent 2-layer LSTM. 256 blocks (1/CU), 4 waves. Block owns 4 hidden
// units (16 gate-rows) of both layers; weights packed bf16 in LDS (112 KB).
// Per-t slabs for h0/h1 -> plain cached loads are never stale; sync is
// per-block release flag stores + relaxed (L2-bypass) spin loads. No L2
// invalidation anywhere, so intra-XCD blocks share h/x lines in L2.
// ---------------------------------------------------------------------------
#define MFMA_STEP(ACC, AIDX, BPTR, BIDX)                                        \
  { u32x4 a_ = sW[AIDX]; u32x4 b_ = (BPTR)[BIDX];                               \
    ACC = __builtin_amdgcn_mfma_f32_16x16x32_bf16(                              \
        *(bf16x8*)&a_, *(bf16x8*)&b_, ACC, 0, 0, 0); }

__global__ __launch_bounds__(256, 1) void lstm_persist(
    const u32x4* __restrict__ xP, u16* __restrict__ h0P, u16* __restrict__ h1P,
    const float* __restrict__ Wih1, const float* __restrict__ Whh1,
    const float* __restrict__ Wih2, const float* __restrict__ Whh2,
    const float* __restrict__ bi1, const float* __restrict__ bh1,
    const float* __restrict__ bi2, const float* __restrict__ bh2,
    int* __restrict__ flags0, int* __restrict__ flags1)
{
  __shared__ u32x4 sW[7168];                  // 112 KB packed weights
  const int tid = threadIdx.x;
  const int blk = blockIdx.x;

  // ---- pack weights fp32 -> bf16 LDS (verified round-2 layout) ----
  for (int i = tid; i < 7168; i += 256){
    int m = i & 15, grp = (i >> 4) & 3, s = i >> 6;
    const float* W; int K, ks;
    if      (s < 16){ W = Wih1; K = 512;  ks = s;      }
    else if (s < 48){ W = Whh1; K = 1024; ks = s - 16; }
    else if (s < 80){ W = Wih2; K = 1024; ks = s - 48; }
    else            { W = Whh2; K = 1024; ks = s - 80; }
    int u = m >> 2, r = m & 3;
    const float* src = W + (size_t)(r*HID + blk*4 + u)*K + ks*32 + grp*8;
    float4 a = *(const float4*)src;
    float4 c = *(const float4*)(src + 4);
    u32x4 o;
    o.x = pack2(a.x, a.y); o.y = pack2(a.z, a.w);
    o.z = pack2(c.x, c.y); o.w = pack2(c.z, c.w);
    sW[i] = o;
  }

  const int w    = tid >> 6, l = tid & 63;
  const int grp  = l >> 4,  col = l & 15;
  const int b    = w*16 + col;
  const int unit = blk*4 + grp;
  const int aoff = grp*16 + col;              // + s*64   (LDS, u32x4 units)
  const int boff = grp*64 + b;                // + s*256  (slab, u32x4 units)
  const int hwo  = (unit >> 3)*512 + b*8 + (unit & 7);

  float bs1[4], bs2[4];
  #pragma unroll
  for (int r = 0; r < 4; ++r){
    bs1[r] = bi1[r*HID + unit] + bh1[r*HID + unit];
    bs2[r] = bi2[r*HID + unit] + bh2[r*HID + unit];
  }
  float c0 = 0.f, c1 = 0.f;
  const u32x4* h04 = (const u32x4*)h0P;
  const u32x4* h14 = (const u32x4*)h1P;
  __syncthreads();

  for (int t = 0; t < TX; ++t){
    // ---- LAYER 1: gates = Wih1·x(t) + Whh1·h0(t) [slab t] ----
    f32x4 acc0 = {0,0,0,0}, acc1 = {0,0,0,0};
    {
      const u32x4* Bx = xP + (size_t)t*4096;
      #pragma unroll
      for (int s = 0; s < 16; s += 2){
        MFMA_STEP(acc0, s*64 + aoff,      Bx, s*256 + boff);
        MFMA_STEP(acc1, (s+1)*64 + aoff,  Bx, (s+1)*256 + boff);
      }
      const u32x4* Bh = h04 + (size_t)t*SLAB_V4;
      #pragma unroll
      for (int s = 0; s < 32; s += 2){
        MFMA_STEP(acc0, (16+s)*64 + aoff, Bh, s*256 + boff);
        MFMA_STEP(acc1, (17+s)*64 + aoff, Bh, (s+1)*256 + boff);
      }
    }
    {
      float p0 = acc0[0]+acc1[0]+bs1[0];
      float p1 = acc0[1]+acc1[1]+bs1[1];
      float p2 = acc0[2]+acc1[2]+bs1[2];
      float p3 = acc0[3]+acc1[3]+bs1[3];
      float iv = sigm(p0), fv = sigm(p1), gv = tanh_(p2), ov = sigm(p3);
      c0 = fv*c0 + iv*gv;
      h0P[(size_t)(t+1)*SLAB_U16 + hwo] = f2bf(ov*tanh_(c0));
    }
    // ---- publish h0(t+1 slab), wait peers (release: wbL2, NO invalidate) --
    __syncthreads();
    if (tid == 0)
      __hip_atomic_store(&flags0[t*NBLK + blk], 1, __ATOMIC_RELEASE,
                         __HIP_MEMORY_SCOPE_AGENT);
    while (__hip_atomic_load(&flags0[t*NBLK + tid], __ATOMIC_RELAXED,
                             __HIP_MEMORY_SCOPE_AGENT) == 0)
      __builtin_amdgcn_s_sleep(1);
    __syncthreads();
    if (t > 0){
      while (__hip_atomic_load(&flags1[(t-1)*NBLK + tid], __ATOMIC_RELAXED,
                               __HIP_MEMORY_SCOPE_AGENT) == 0)
        __builtin_amdgcn_s_sleep(1);
      __syncthreads();
    }
    // ---- LAYER 2: gates = Wih2·h0(t+1 slab) + Whh2·h1(t) [slab t] ----
    f32x4 d0 = {0,0,0,0}, d1 = {0,0,0,0};
    {
      const u32x4* Bh0 = h04 + (size_t)(t+1)*SLAB_V4;
      #pragma unroll
      for (int s = 0; s < 32; s += 2){
        MFMA_STEP(d0, (48+s)*64 + aoff, Bh0, s*256 + boff);
        MFMA_STEP(d1, (49+s)*64 + aoff, Bh0, (s+1)*256 + boff);
      }
      const u32x4* Bh1 = h14 + (size_t)t*SLAB_V4;
      #pragma unroll
      for (int s = 0; s < 32; s += 2){
        MFMA_STEP(d0, (80+s)*64 + aoff, Bh1, s*256 + boff);
        MFMA_STEP(d1, (81+s)*64 + aoff, Bh1, (s+1)*256 + boff);
      }
    }
    {
      float p0 = d0[0]+d1[0]+bs2[0];
      float p1 = d0[1]+d1[1]+bs2[1];
      float p2 = d0[2]+d1[2]+bs2[2];
      float p3 = d0[3]+d1[3]+bs2[3];
      float iv = sigm(p0), fv = sigm(p1), gv = tanh_(p2), ov = sigm(p3);
      c1 = fv*c1 + iv*gv;
      h1P[(size_t)(t+1)*SLAB_U16 + hwo] = f2bf(ov*tanh_(c1));
    }
    __syncthreads();
    if (tid == 0)
      __hip_atomic_store(&flags1[t*NBLK + blk], 1, __ATOMIC_RELEASE,
                         __HIP_MEMORY_SCOPE_AGENT);
    // next iter's L2 waits flags1[t] before touching h1(t+1 slab)
  }
}

// ---------------------------------------------------------------------------
// out[t][b][v] = sum_k h1(t)[k][b] * W_out[v][k] + b_out[v]   (fp32 VALU)
// ---------------------------------------------------------------------------
__global__ __launch_bounds__(256) void out_gemm(
    const u16* __restrict__ h1P, const float* __restrict__ W_out,
    const float* __restrict__ b_out, float* __restrict__ out)
{
  const int t  = blockIdx.x;
  const int v0 = blockIdx.y * 64;

  __shared__ float As[16*64];
  __shared__ float Bs[64][17];

  const int tid = threadIdx.x, lane = tid & 63, w = tid >> 6;
  float acc[16];
  #pragma unroll
  for (int m = 0; m < 16; ++m) acc[m] = 0.f;

  const u16* hs = h1P + (size_t)(t+1)*SLAB_U16;

  for (int kb = 0; kb < HID; kb += 16){
    __syncthreads();
    {
      const u32* src = (const u32*)(hs + (kb >> 3)*512);
      u32 p0 = src[tid*2], p1 = src[tid*2+1];
      int e  = tid*4;
      int i0 = e & 7;
      int bb = (e >> 3) & 63;
      int kk = (e >> 9)*8 + i0;
      As[(kk+0)*64 + bb] = bf2f((u16)(p0 & 0xffffu));
      As[(kk+1)*64 + bb] = bf2f((u16)(p0 >> 16));
      As[(kk+2)*64 + bb] = bf2f((u16)(p1 & 0xffffu));
      As[(kk+3)*64 + bb] = bf2f((u16)(p1 >> 16));
    }
    {
      int i = tid >> 2, kc = (tid & 3)*4;
      float4 wv = *(const float4*)(W_out + (size_t)(v0+i)*HID + kb + kc);
      Bs[i][kc+0] = wv.x; Bs[i][kc+1] = wv.y;
      Bs[i][kc+2] = wv.z; Bs[i][kc+3] = wv.w;
    }
    __syncthreads();

    #pragma unroll
    for (int kk = 0; kk < 16; ++kk){
      float wv = Bs[lane][kk];
      #pragma unroll
      for (int m = 0; m < 16; ++m)
        acc[m] += wv * As[kk*64 + w*16 + m];
    }
  }

  const float bo = b_out[v0 + lane];
  #pragma unroll
  for (int m = 0; m < 16; ++m){
    int bb = w*16 + m;
    out[((size_t)t*BATCH + bb)*VOCAB + v0 + lane] = acc[m] + bo;
  }
}

// ---------------------------------------------------------------------------
extern "C" void kernel_launch(void* const* d_in, const int* in_sizes, int n_in,
                              void* d_out, int out_size, void* d_ws, size_t ws_size,
                              hipStream_t stream)
{
  const int*   x     = (const int*)  d_in[0];
  const float* emb   = (const float*)d_in[1];
  const float* W_ih1 = (const float*)d_in[2];
  const float* W_hh1 = (const float*)d_in[3];
  const float* b_ih1 = (const float*)d_in[4];
  const float* b_hh1 = (const float*)d_in[5];
  const float* W_ih2 = (const float*)d_in[6];
  const float* W_hh2 = (const float*)d_in[7];
  const float* b_ih2 = (const float*)d_in[8];
  const float* b_hh2 = (const float*)d_in[9];
  const float* W_out = (const float*)d_in[10];
  const float* b_out = (const float*)d_in[11];
  float* out = (float*)d_out;

  char* ws = (char*)d_ws;
  int*   flags0 = (int*)  (ws + OFF_FLAGS0);
  int*   flags1 = (int*)  (ws + OFF_FLAGS1);
  u16*   h0P    = (u16*)  (ws + OFF_H0);
  u16*   h1P    = (u16*)  (ws + OFF_H1);
  u32x4* xP     = (u32x4*)(ws + OFF_XP);

  hipMemsetAsync(ws + OFF_FLAGS0, 0, 524288, stream);  // both flag arrays
  hipMemsetAsync(ws + OFF_H0, 0, 131072, stream);      // h0 slab 0 = zeros
  hipMemsetAsync(ws + OFF_H1, 0, 131072, stream);      // h1 slab 0 = zeros

  embed_pack<<<4096, 256, 0, stream>>>(x, emb, xP);

  lstm_persist<<<NBLK, 256, 0, stream>>>(
      xP, h0P, h1P, W_ih1, W_hh1, W_ih2, W_hh2,
      b_ih1, b_hh1, b_ih2, b_hh2, flags0, flags1);

  dim3 og(TX, VOCAB/64);
  out_gemm<<<og, 256, 0, stream>>>(h1P, W_out, b_out, out);
}

// Round 4
// 2722.024 us; speedup vs baseline: 2.1583x; 2.1583x over previous
//
#include <hip/hip_runtime.h>
#include <math.h>
#include <stdint.h>

#define VOCAB 2048
#define EMB   512
#define HID   1024
#define TX    256
#define BATCH 64
#define NBLK  256

typedef __attribute__((ext_vector_type(8))) short bf16x8;
typedef __attribute__((ext_vector_type(4))) float f32x4;
typedef unsigned int u32;
typedef unsigned short u16;
typedef __attribute__((ext_vector_type(4))) u32 u32x4;

// ---------------- ws byte offsets ----------------
// flags0/1 : [256 t][256 blk] int   (memset 0 each launch)
// h0P      : 257 slabs of [128 kblk][64 b][8] bf16  (slab t+1 = h0 at step t)
// h1P      : 257 slabs, same layout (slab 0 zeroed)
// xP       : [TX][64 kblk][64 b][8] bf16
#define OFF_FLAGS0 0u
#define OFF_FLAGS1 262144u
#define OFF_H0     524288u
#define OFF_H1     34209792u
#define OFF_XP     67895296u
#define SLAB_U16   65536u
#define SLAB_U32   32768u
#define SLAB_V4    8192u

__device__ __forceinline__ u16 f2bf(float x){
  u32 v = __float_as_uint(x);
  v += 0x7fffu + ((v >> 16) & 1u);          // RNE
  return (u16)(v >> 16);
}
__device__ __forceinline__ u32 pack2(float a, float b){
  return (u32)f2bf(a) | ((u32)f2bf(b) << 16);
}
__device__ __forceinline__ float bf2f(u16 h){ return __uint_as_float(((u32)h) << 16); }
__device__ __forceinline__ float sigm(float x){ return 1.f/(1.f+__expf(-x)); }
__device__ __forceinline__ float tanh_(float x){
  float e = __expf(2.f*fabsf(x));           // overflow-safe
  return copysignf(1.f - 2.f/(e+1.f), x);
}

// ---------------------------------------------------------------------------
__global__ __launch_bounds__(256) void embed_pack(
    const int* __restrict__ x, const float* __restrict__ emb, u32x4* __restrict__ xP)
{
  int flat = blockIdx.x*256 + threadIdx.x;   // t*4096 + kblk*64 + b
  int b    = flat & 63;
  int kblk = (flat >> 6) & 63;
  int t    = flat >> 12;
  int idx  = x[b*TX + t];
  const float* src = emb + (size_t)idx*EMB + kblk*8;
  u32x4 o;
  o.x = pack2(src[0], src[1]);
  o.y = pack2(src[2], src[3]);
  o.z = pack2(src[4], src[5]);
  o.w = pack2(src[6], src[7]);
  xP[flat] = o;
}

// ---------------------------------------------------------------------------
// Persistent 2-layer LSTM. 256 blocks (1/CU), 4 waves. Block owns 4 hidden
// units (16 gate-rows); weights bf16 in LDS (112 KB). Sync protocol is
// cache-maintenance-free: h published via agent-scope relaxed atomic u32
// stores (L3-direct, no wbl2), flags via relaxed agent atomics; per-wave
// store drain comes from the s_waitcnt vmcnt(0) the compiler emits before
// every s_barrier. Polls overlap with independent MFMA work.
// ---------------------------------------------------------------------------
#define MFMA_STEP(ACC, AIDX, BPTR, BIDX)                                        \
  { u32x4 a_ = sW[AIDX]; u32x4 b_ = (BPTR)[BIDX];                               \
    ACC = __builtin_amdgcn_mfma_f32_16x16x32_bf16(                              \
        *(bf16x8*)&a_, *(bf16x8*)&b_, ACC, 0, 0, 0); }

__global__ __launch_bounds__(256, 1) void lstm_persist(
    const u32x4* __restrict__ xP, u16* __restrict__ h0P, u16* __restrict__ h1P,
    const float* __restrict__ Wih1, const float* __restrict__ Whh1,
    const float* __restrict__ Wih2, const float* __restrict__ Whh2,
    const float* __restrict__ bi1, const float* __restrict__ bh1,
    const float* __restrict__ bi2, const float* __restrict__ bh2,
    int* __restrict__ flags0, int* __restrict__ flags1)
{
  __shared__ u32x4 sW[7168];                  // 112 KB packed weights
  const int tid = threadIdx.x;
  const int blk = blockIdx.x;

  // ---- pack weights fp32 -> bf16 LDS (verified layout) ----
  for (int i = tid; i < 7168; i += 256){
    int m = i & 15, grp_ = (i >> 4) & 3, s = i >> 6;
    const float* W; int K, ks;
    if      (s < 16){ W = Wih1; K = 512;  ks = s;      }
    else if (s < 48){ W = Whh1; K = 1024; ks = s - 16; }
    else if (s < 80){ W = Wih2; K = 1024; ks = s - 48; }
    else            { W = Whh2; K = 1024; ks = s - 80; }
    int u = m >> 2, r = m & 3;
    const float* src = W + (size_t)(r*HID + blk*4 + u)*K + ks*32 + grp_*8;
    float4 a = *(const float4*)src;
    float4 c = *(const float4*)(src + 4);
    u32x4 o;
    o.x = pack2(a.x, a.y); o.y = pack2(a.z, a.w);
    o.z = pack2(c.x, c.y); o.w = pack2(c.z, c.w);
    sW[i] = o;
  }

  const int w    = tid >> 6, l = tid & 63;
  const int grp  = l >> 4,  col = l & 15;
  const int b    = w*16 + col;
  const int unit = blk*4 + grp;
  const int aoff = grp*16 + col;              // + s*64   (LDS, u32x4 units)
  const int boff = grp*64 + b;                // + s*256  (slab, u32x4 units)
  // paired-u32 write offset (valid on even-grp lanes)
  const int pwo  = (unit >> 3)*256 + b*4 + ((unit & 7) >> 1);

  float bs1[4], bs2[4];
  #pragma unroll
  for (int r = 0; r < 4; ++r){
    bs1[r] = bi1[r*HID + unit] + bh1[r*HID + unit];
    bs2[r] = bi2[r*HID + unit] + bh2[r*HID + unit];
  }
  float c0 = 0.f, c1 = 0.f;
  const u32x4* h04 = (const u32x4*)h0P;
  const u32x4* h14 = (const u32x4*)h1P;
  u32* h0w = (u32*)h0P;
  u32* h1w = (u32*)h1P;
  __syncthreads();

  for (int t = 0; t < TX; ++t){
    // ---- LAYER 1: gates = Wih1·x(t) + Whh1·h0(t) ----
    f32x4 acc0 = {0,0,0,0}, acc1 = {0,0,0,0};
    {
      const u32x4* Bx = xP + (size_t)t*4096;
      #pragma unroll
      for (int s = 0; s < 16; s += 2){
        MFMA_STEP(acc0, s*64 + aoff,      Bx, s*256 + boff);
        MFMA_STEP(acc1, (s+1)*64 + aoff,  Bx, (s+1)*256 + boff);
      }
      const u32x4* Bh = h04 + (size_t)t*SLAB_V4;
      #pragma unroll
      for (int s = 0; s < 32; s += 2){
        MFMA_STEP(acc0, (16+s)*64 + aoff, Bh, s*256 + boff);
        MFMA_STEP(acc1, (17+s)*64 + aoff, Bh, (s+1)*256 + boff);
      }
    }
    {
      float p0 = acc0[0]+acc1[0]+bs1[0];
      float p1 = acc0[1]+acc1[1]+bs1[1];
      float p2 = acc0[2]+acc1[2]+bs1[2];
      float p3 = acc0[3]+acc1[3]+bs1[3];
      float iv = sigm(p0), fv = sigm(p1), gv = tanh_(p2), ov = sigm(p3);
      c0 = fv*c0 + iv*gv;
      u32 mine = f2bf(ov*tanh_(c0));
      u32 part = (u32)__shfl_xor((int)mine, 16, 64);
      if (!(grp & 1))
        __hip_atomic_store(h0w + (size_t)(t+1)*SLAB_U32 + pwo,
                           mine | (part << 16),
                           __ATOMIC_RELAXED, __HIP_MEMORY_SCOPE_AGENT);
    }
    __syncthreads();   // drains each wave's stores (vmcnt0 before s_barrier)
    if (tid == 0)
      __hip_atomic_store(&flags0[t*NBLK + blk], 1, __ATOMIC_RELAXED,
                         __HIP_MEMORY_SCOPE_AGENT);

    // ---- LAYER 2a: d = Whh2·h1(t)  (flags1(t-1) is long-satisfied) ----
    f32x4 d0 = {0,0,0,0}, d1 = {0,0,0,0};
    if (t > 0){
      int* f1row = flags1 + (t-1)*NBLK;
      while (__hip_atomic_load(&f1row[tid], __ATOMIC_RELAXED,
                               __HIP_MEMORY_SCOPE_AGENT) == 0)
        __builtin_amdgcn_s_sleep(2);
    }
    __syncthreads();
    {
      const u32x4* Bh1 = h14 + (size_t)t*SLAB_V4;
      #pragma unroll
      for (int s = 0; s < 32; s += 2){
        MFMA_STEP(d0, (80+s)*64 + aoff, Bh1, s*256 + boff);
        MFMA_STEP(d1, (81+s)*64 + aoff, Bh1, (s+1)*256 + boff);
      }
    }
    // ---- wait for h0(t+1) from all blocks, then LAYER 2b ----
    {
      int* f0row = flags0 + t*NBLK;
      while (__hip_atomic_load(&f0row[tid], __ATOMIC_RELAXED,
                               __HIP_MEMORY_SCOPE_AGENT) == 0)
        __builtin_amdgcn_s_sleep(2);
    }
    __syncthreads();
    {
      const u32x4* Bh0 = h04 + (size_t)(t+1)*SLAB_V4;
      #pragma unroll
      for (int s = 0; s < 32; s += 2){
        MFMA_STEP(d0, (48+s)*64 + aoff, Bh0, s*256 + boff);
        MFMA_STEP(d1, (49+s)*64 + aoff, Bh0, (s+1)*256 + boff);
      }
    }
    {
      float p0 = d0[0]+d1[0]+bs2[0];
      float p1 = d0[1]+d1[1]+bs2[1];
      float p2 = d0[2]+d1[2]+bs2[2];
      float p3 = d0[3]+d1[3]+bs2[3];
      float iv = sigm(p0), fv = sigm(p1), gv = tanh_(p2), ov = sigm(p3);
      c1 = fv*c1 + iv*gv;
      u32 mine = f2bf(ov*tanh_(c1));
      u32 part = (u32)__shfl_xor((int)mine, 16, 64);
      if (!(grp & 1))
        __hip_atomic_store(h1w + (size_t)(t+1)*SLAB_U32 + pwo,
                           mine | (part << 16),
                           __ATOMIC_RELAXED, __HIP_MEMORY_SCOPE_AGENT);
    }
    __syncthreads();   // drain h1 stores
    if (tid == 0)
      __hip_atomic_store(&flags1[t*NBLK + blk], 1, __ATOMIC_RELAXED,
                         __HIP_MEMORY_SCOPE_AGENT);
  }
}

// ---------------------------------------------------------------------------
// out[t][b][v] = sum_k h1(t)[k][b] * W_out[v][k] + b_out[v]   (fp32 VALU)
// ---------------------------------------------------------------------------
__global__ __launch_bounds__(256) void out_gemm(
    const u16* __restrict__ h1P, const float* __restrict__ W_out,
    const float* __restrict__ b_out, float* __restrict__ out)
{
  const int t  = blockIdx.x;
  const int v0 = blockIdx.y * 64;

  __shared__ float As[16*64];
  __shared__ float Bs[64][17];

  const int tid = threadIdx.x, lane = tid & 63, w = tid >> 6;
  float acc[16];
  #pragma unroll
  for (int m = 0; m < 16; ++m) acc[m] = 0.f;

  const u16* hs = h1P + (size_t)(t+1)*SLAB_U16;

  for (int kb = 0; kb < HID; kb += 16){
    __syncthreads();
    {
      const u32* src = (const u32*)(hs + (kb >> 3)*512);
      u32 p0 = src[tid*2], p1 = src[tid*2+1];
      int e  = tid*4;
      int i0 = e & 7;
      int bb = (e >> 3) & 63;
      int kk = (e >> 9)*8 + i0;
      As[(kk+0)*64 + bb] = bf2f((u16)(p0 & 0xffffu));
      As[(kk+1)*64 + bb] = bf2f((u16)(p0 >> 16));
      As[(kk+2)*64 + bb] = bf2f((u16)(p1 & 0xffffu));
      As[(kk+3)*64 + bb] = bf2f((u16)(p1 >> 16));
    }
    {
      int i = tid >> 2, kc = (tid & 3)*4;
      float4 wv = *(const float4*)(W_out + (size_t)(v0+i)*HID + kb + kc);
      Bs[i][kc+0] = wv.x; Bs[i][kc+1] = wv.y;
      Bs[i][kc+2] = wv.z; Bs[i][kc+3] = wv.w;
    }
    __syncthreads();

    #pragma unroll
    for (int kk = 0; kk < 16; ++kk){
      float wv = Bs[lane][kk];
      #pragma unroll
      for (int m = 0; m < 16; ++m)
        acc[m] += wv * As[kk*64 + w*16 + m];
    }
  }

  const float bo = b_out[v0 + lane];
  #pragma unroll
  for (int m = 0; m < 16; ++m){
    int bb = w*16 + m;
    out[((size_t)t*BATCH + bb)*VOCAB + v0 + lane] = acc[m] + bo;
  }
}

// ---------------------------------------------------------------------------
extern "C" void kernel_launch(void* const* d_in, const int* in_sizes, int n_in,
                              void* d_out, int out_size, void* d_ws, size_t ws_size,
                              hipStream_t stream)
{
  const int*   x     = (const int*)  d_in[0];
  const float* emb   = (const float*)d_in[1];
  const float* W_ih1 = (const float*)d_in[2];
  const float* W_hh1 = (const float*)d_in[3];
  const float* b_ih1 = (const float*)d_in[4];
  const float* b_hh1 = (const float*)d_in[5];
  const float* W_ih2 = (const float*)d_in[6];
  const float* W_hh2 = (const float*)d_in[7];
  const float* b_ih2 = (const float*)d_in[8];
  const float* b_hh2 = (const float*)d_in[9];
  const float* W_out = (const float*)d_in[10];
  const float* b_out = (const float*)d_in[11];
  float* out = (float*)d_out;

  char* ws = (char*)d_ws;
  int*   flags0 = (int*)  (ws + OFF_FLAGS0);
  int*   flags1 = (int*)  (ws + OFF_FLAGS1);
  u16*   h0P    = (u16*)  (ws + OFF_H0);
  u16*   h1P    = (u16*)  (ws + OFF_H1);
  u32x4* xP     = (u32x4*)(ws + OFF_XP);

  hipMemsetAsync(ws + OFF_FLAGS0, 0, 524288, stream);  // both flag arrays
  hipMemsetAsync(ws + OFF_H0, 0, 131072, stream);      // h0 slab 0 = zeros
  hipMemsetAsync(ws + OFF_H1, 0, 131072, stream);      // h1 slab 0 = zeros

  embed_pack<<<4096, 256, 0, stream>>>(x, emb, xP);

  lstm_persist<<<NBLK, 256, 0, stream>>>(
      xP, h0P, h1P, W_ih1, W_hh1, W_ih2, W_hh2,
      b_ih1, b_hh1, b_ih2, b_hh2, flags0, flags1);

  dim3 og(TX, VOCAB/64);
  out_gemm<<<og, 256, 0, stream>>>(h1P, W_out, b_out, out);
}

// Round 5
// 1969.166 us; speedup vs baseline: 2.9835x; 1.3823x over previous
//
#include <hip/hip_runtime.h>
#include <math.h>
#include <stdint.h>

#define VOCAB 2048
#define EMB   512
#define HID   1024
#define TX    256
#define BATCH 64

typedef __attribute__((ext_vector_type(8))) short bf16x8;
typedef __attribute__((ext_vector_type(4))) float f32x4;
typedef unsigned int u32;
typedef unsigned short u16;
typedef __attribute__((ext_vector_type(4))) u32 u32x4;

// ---------------- ws byte offsets ----------------
// flags0 : [256 t][128 L1-blk] int   (memset 0 each launch)
// flags1 : [256 t][128 L2-blk] int
// h0P    : 257 slabs of [128 kblk][64 b][8] bf16  (slab t+1 = h0 after step t)
// h1P    : 257 slabs, same layout (slab 0 zeroed)
// xP     : [TX][64 kblk][64 b][8] bf16
#define OFF_FLAGS0 0u
#define OFF_FLAGS1 131072u
#define OFF_H0     262144u
#define OFF_H1     33947648u
#define OFF_XP     67633152u
#define SLAB_U16   65536u
#define SLAB_U32   32768u
#define SLAB_V4    8192u

__device__ __forceinline__ u16 f2bf(float x){
  u32 v = __float_as_uint(x);
  v += 0x7fffu + ((v >> 16) & 1u);          // RNE
  return (u16)(v >> 16);
}
__device__ __forceinline__ u32 pack2(float a, float b){
  return (u32)f2bf(a) | ((u32)f2bf(b) << 16);
}
__device__ __forceinline__ float bf2f(u16 h){ return __uint_as_float(((u32)h) << 16); }
__device__ __forceinline__ float sigm(float x){ return 1.f/(1.f+__expf(-x)); }
__device__ __forceinline__ float tanh_(float x){
  float e = __expf(2.f*fabsf(x));           // overflow-safe
  return copysignf(1.f - 2.f/(e+1.f), x);
}

// ---------------------------------------------------------------------------
__global__ __launch_bounds__(256) void embed_pack(
    const int* __restrict__ x, const float* __restrict__ emb, u32x4* __restrict__ xP)
{
  int flat = blockIdx.x*256 + threadIdx.x;   // t*4096 + kblk*64 + b
  int b    = flat & 63;
  int kblk = (flat >> 6) & 63;
  int t    = flat >> 12;
  int idx  = x[b*TX + t];
  const float* src = emb + (size_t)idx*EMB + kblk*8;
  u32x4 o;
  o.x = pack2(src[0], src[1]);
  o.y = pack2(src[2], src[3]);
  o.z = pack2(src[4], src[5]);
  o.w = pack2(src[6], src[7]);
  xP[flat] = o;
}

// ---------------------------------------------------------------------------
// Layer-specialized persistent LSTM. Blocks 0..127 = layer 1 (8 units each,
// 96 KB LDS); blocks 128..255 = layer 2 (8 units, 128 KB LDS). The two
// recurrence chains advance concurrently (pipeline depth 2); each chain pays
// one publish->L3->detect round trip per step. Sync protocol identical to
// the validated round-4 one: relaxed agent atomic h-stores + barrier drain +
// relaxed flag stores; consumers poll flags with relaxed agent atomic loads
// and read h slabs with plain cached loads (fresh per-t addresses).
// ---------------------------------------------------------------------------
#define MFMA(ACC, AV, BV)                                                       \
  ACC = __builtin_amdgcn_mfma_f32_16x16x32_bf16(                                \
      *(bf16x8*)&(AV), *(bf16x8*)&(BV), ACC, 0, 0, 0)

__device__ __forceinline__ u32 cell_h(const f32x4& A, const f32x4& B,
                                      const float* bs, float& c){
  float p0=A[0]+B[0]+bs[0], p1=A[1]+B[1]+bs[1];
  float p2=A[2]+B[2]+bs[2], p3=A[3]+B[3]+bs[3];
  float iv=sigm(p0), fv=sigm(p1), gv=tanh_(p2), ov=sigm(p3);
  c = fv*c + iv*gv;
  return (u32)f2bf(ov*tanh_(c));
}

__global__ __launch_bounds__(256, 1) void lstm_persist(
    const u32x4* __restrict__ xP, u16* __restrict__ h0P, u16* __restrict__ h1P,
    const float* __restrict__ Wih1, const float* __restrict__ Whh1,
    const float* __restrict__ Wih2, const float* __restrict__ Whh2,
    const float* __restrict__ bi1, const float* __restrict__ bh1,
    const float* __restrict__ bi2, const float* __restrict__ bh2,
    int* __restrict__ flags0, int* __restrict__ flags1)
{
  __shared__ u32x4 sW[8192];                  // 128 KB
  const int tid = threadIdx.x;
  const int blk = blockIdx.x;
  const bool isL1 = (blk < 128);
  const int  lblk = isL1 ? blk : (blk - 128);

  // ---- pack this block's weight slice fp32 -> bf16 LDS ----
  // section s: L1: s<16 Wih1(K=512), s<48 Whh1(K=1024)
  //            L2: s<32 Wih2(K=1024), s<64 Whh2(K=1024)
  // idx = (s*2 + T)*64 + grp*16 + m ; row = r*1024 + lblk*8 + T*4 + u
  {
    const int nsec = isL1 ? 6144 : 8192;
    for (int i = tid; i < nsec; i += 256){
      int m = i & 15, grp_ = (i >> 4) & 3, T = (i >> 6) & 1, s = i >> 7;
      const float* W; int K, ks;
      if (isL1){
        if (s < 16){ W = Wih1; K = 512;  ks = s;      }
        else       { W = Whh1; K = 1024; ks = s - 16; }
      } else {
        if (s < 32){ W = Wih2; K = 1024; ks = s;      }
        else       { W = Whh2; K = 1024; ks = s - 32; }
      }
      int u = m >> 2, r = m & 3;
      const float* src = W + (size_t)(r*HID + lblk*8 + T*4 + u)*K + ks*32 + grp_*8;
      float4 a = *(const float4*)src;
      float4 c = *(const float4*)(src + 4);
      u32x4 o;
      o.x = pack2(a.x, a.y); o.y = pack2(a.z, a.w);
      o.z = pack2(c.x, c.y); o.w = pack2(c.z, c.w);
      sW[i] = o;
    }
  }

  const int w    = tid >> 6, l = tid & 63;
  const int grp  = l >> 4,  col = l & 15;
  const int b    = w*16 + col;
  const int aoff = l;                         // A-frag LDS offset within section
  const int boff = grp*64 + b;                // B-frag offset within slab (u32x4)

  const int unitA = lblk*8 + grp;             // tile 0
  const int unitB = lblk*8 + 4 + grp;         // tile 1
  float bsA[4], bsB[4];
  #pragma unroll
  for (int r = 0; r < 4; ++r){
    if (isL1){
      bsA[r] = bi1[r*HID + unitA] + bh1[r*HID + unitA];
      bsB[r] = bi1[r*HID + unitB] + bh1[r*HID + unitB];
    } else {
      bsA[r] = bi2[r*HID + unitA] + bh2[r*HID + unitA];
      bsB[r] = bi2[r*HID + unitB] + bh2[r*HID + unitB];
    }
  }
  float cA = 0.f, cB = 0.f;
  const u32x4* h04 = (const u32x4*)h0P;
  const u32x4* h14 = (const u32x4*)h1P;
  u32* h0w = (u32*)h0P;
  u32* h1w = (u32*)h1P;
  __syncthreads();

  if (isL1){
    // ================= LAYER-1 blocks =================
    for (int t = 0; t < TX; ++t){
      f32x4 a00={0,0,0,0}, a01={0,0,0,0}, a10={0,0,0,0}, a11={0,0,0,0};
      // x-part (independent of recurrence) — hides part of the flag wait
      {
        const u32x4* Bx = xP + (size_t)t*4096;
        #pragma unroll
        for (int s = 0; s < 16; s += 2){
          u32x4 B0 = Bx[s*256 + boff], B1 = Bx[(s+1)*256 + boff];
          MFMA(a00, sW[(s*2+0)*64 + aoff], B0);
          MFMA(a10, sW[(s*2+1)*64 + aoff], B0);
          MFMA(a01, sW[(s*2+2)*64 + aoff], B1);
          MFMA(a11, sW[(s*2+3)*64 + aoff], B1);
        }
      }
      if (t > 0){
        int* row = flags0 + (t-1)*128;
        if (tid < 128)
          while (__hip_atomic_load(&row[tid], __ATOMIC_RELAXED,
                                   __HIP_MEMORY_SCOPE_AGENT) == 0)
            __builtin_amdgcn_s_sleep(2);
        __syncthreads();
      }
      {
        const u32x4* Bh = h04 + (size_t)t*SLAB_V4;
        #pragma unroll
        for (int s = 0; s < 32; s += 2){
          u32x4 B0 = Bh[s*256 + boff], B1 = Bh[(s+1)*256 + boff];
          MFMA(a00, sW[((16+s)*2+0)*64 + aoff], B0);
          MFMA(a10, sW[((16+s)*2+1)*64 + aoff], B0);
          MFMA(a01, sW[((17+s)*2+0)*64 + aoff], B1);
          MFMA(a11, sW[((17+s)*2+1)*64 + aoff], B1);
        }
      }
      {
        u32 m0 = cell_h(a00, a01, bsA, cA);
        u32 m1 = cell_h(a10, a11, bsB, cB);
        u32 p0 = (u32)__shfl_xor((int)m0, 16, 64);
        u32 p1 = (u32)__shfl_xor((int)m1, 16, 64);
        if (!(grp & 1)){
          u32* base = h0w + (size_t)(t+1)*SLAB_U32 + lblk*256 + b*4 + (grp>>1);
          __hip_atomic_store(base,     m0 | (p0<<16),
                             __ATOMIC_RELAXED, __HIP_MEMORY_SCOPE_AGENT);
          __hip_atomic_store(base + 2, m1 | (p1<<16),
                             __ATOMIC_RELAXED, __HIP_MEMORY_SCOPE_AGENT);
        }
      }
      __syncthreads();   // drains stores (vmcnt0 before s_barrier)
      if (tid == 0)
        __hip_atomic_store(&flags0[t*128 + lblk], 1, __ATOMIC_RELAXED,
                           __HIP_MEMORY_SCOPE_AGENT);
    }
  } else {
    // ================= LAYER-2 blocks =================
    for (int t = 0; t < TX; ++t){
      f32x4 a00={0,0,0,0}, a01={0,0,0,0}, a10={0,0,0,0}, a11={0,0,0,0};
      // wait h1(t) from own group, then h1-part
      if (t > 0){
        int* row = flags1 + (t-1)*128;
        if (tid < 128)
          while (__hip_atomic_load(&row[tid], __ATOMIC_RELAXED,
                                   __HIP_MEMORY_SCOPE_AGENT) == 0)
            __builtin_amdgcn_s_sleep(2);
        __syncthreads();
      }
      {
        const u32x4* Bh = h14 + (size_t)t*SLAB_V4;
        #pragma unroll
        for (int s = 0; s < 32; s += 2){
          u32x4 B0 = Bh[s*256 + boff], B1 = Bh[(s+1)*256 + boff];
          MFMA(a00, sW[((32+s)*2+0)*64 + aoff], B0);
          MFMA(a10, sW[((32+s)*2+1)*64 + aoff], B0);
          MFMA(a01, sW[((33+s)*2+0)*64 + aoff], B1);
          MFMA(a11, sW[((33+s)*2+1)*64 + aoff], B1);
        }
      }
      // wait h0(t+1) from layer-1 group (pipeline-hidden in steady state)
      {
        int* row = flags0 + t*128;
        if (tid < 128)
          while (__hip_atomic_load(&row[tid], __ATOMIC_RELAXED,
                                   __HIP_MEMORY_SCOPE_AGENT) == 0)
            __builtin_amdgcn_s_sleep(2);
        __syncthreads();
      }
      {
        const u32x4* Bh = h04 + (size_t)(t+1)*SLAB_V4;
        #pragma unroll
        for (int s = 0; s < 32; s += 2){
          u32x4 B0 = Bh[s*256 + boff], B1 = Bh[(s+1)*256 + boff];
          MFMA(a00, sW[(s*2+0)*64 + aoff], B0);
          MFMA(a10, sW[(s*2+1)*64 + aoff], B0);
          MFMA(a01, sW[((s+1)*2+0)*64 + aoff], B1);
          MFMA(a11, sW[((s+1)*2+1)*64 + aoff], B1);
        }
      }
      {
        u32 m0 = cell_h(a00, a01, bsA, cA);
        u32 m1 = cell_h(a10, a11, bsB, cB);
        u32 p0 = (u32)__shfl_xor((int)m0, 16, 64);
        u32 p1 = (u32)__shfl_xor((int)m1, 16, 64);
        if (!(grp & 1)){
          u32* base = h1w + (size_t)(t+1)*SLAB_U32 + lblk*256 + b*4 + (grp>>1);
          __hip_atomic_store(base,     m0 | (p0<<16),
                             __ATOMIC_RELAXED, __HIP_MEMORY_SCOPE_AGENT);
          __hip_atomic_store(base + 2, m1 | (p1<<16),
                             __ATOMIC_RELAXED, __HIP_MEMORY_SCOPE_AGENT);
        }
      }
      __syncthreads();
      if (tid == 0)
        __hip_atomic_store(&flags1[t*128 + lblk], 1, __ATOMIC_RELAXED,
                           __HIP_MEMORY_SCOPE_AGENT);
    }
  }
}

// ---------------------------------------------------------------------------
// MFMA output projection with split-precision W_out (bf16 hi + bf16 lo).
// GEMM view: M=2048(v) x N=16384(t,b) x K=1024. Block tile: 128 v x 256 n
// (4 t x 64 b). A (W hi/lo) staged per-256-K-chunk in LDS; B read direct
// from h1P slabs; C transposed through LDS for dense fp32 stores.
// ---------------------------------------------------------------------------
__global__ __launch_bounds__(256, 1) void out_gemm(
    const u16* __restrict__ h1P, const float* __restrict__ W_out,
    const float* __restrict__ b_out, float* __restrict__ out)
{
  __shared__ u32x4 sA[8192];                  // 128 KB (A hi/lo chunk; C reuse)
  const int tid = threadIdx.x, l = tid & 63, w = tid >> 6;
  const int grp = l >> 4, col = l & 15;
  const int b   = w*16 + col;
  const int vbase = blockIdx.x * 128;
  const int t0    = blockIdx.y * 4;

  f32x4 acc0[8], acc1[8], acc2[8], acc3[8];
  #pragma unroll
  for (int m = 0; m < 8; ++m){
    acc0[m]=(f32x4){0,0,0,0}; acc1[m]=(f32x4){0,0,0,0};
    acc2[m]=(f32x4){0,0,0,0}; acc3[m]=(f32x4){0,0,0,0};
  }
  const u32x4* h14 = (const u32x4*)h1P;

  for (int kc = 0; kc < 4; ++kc){
    __syncthreads();
    // stage A: W_out rows vbase..vbase+127, k-chunk kc*256.., hi+lo bf16
    #pragma unroll
    for (int k = 0; k < 16; ++k){
      int j = tid + k*256;                    // (s, mt, lane)
      int lane = j & 63, mt = (j >> 6) & 7, s = j >> 9;
      int v  = vbase + mt*16 + (lane & 15);
      int kk = kc*256 + s*32 + (lane >> 4)*8;
      const float* src = W_out + (size_t)v*HID + kk;
      float4 f0 = *(const float4*)src, f1 = *(const float4*)(src + 4);
      float e[8] = {f0.x,f0.y,f0.z,f0.w,f1.x,f1.y,f1.z,f1.w};
      u16 hi[8]; float lo[8];
      #pragma unroll
      for (int r = 0; r < 8; ++r){ hi[r] = f2bf(e[r]); lo[r] = e[r] - bf2f(hi[r]); }
      u32x4 H, L;
      H.x = (u32)hi[0]|((u32)hi[1]<<16); H.y = (u32)hi[2]|((u32)hi[3]<<16);
      H.z = (u32)hi[4]|((u32)hi[5]<<16); H.w = (u32)hi[6]|((u32)hi[7]<<16);
      L.x = pack2(lo[0],lo[1]); L.y = pack2(lo[2],lo[3]);
      L.z = pack2(lo[4],lo[5]); L.w = pack2(lo[6],lo[7]);
      int base = (s*8 + mt)*128 + lane;       // hl interleave: +64 for lo
      sA[base]      = H;
      sA[base + 64] = L;
    }
    __syncthreads();

    #pragma unroll
    for (int s = 0; s < 8; ++s){
      int ksl = kc*8 + s;
      int bi  = ksl*256 + grp*64 + b;
      u32x4 B0 = h14[(size_t)(t0+1)*SLAB_V4 + bi];
      u32x4 B1 = h14[(size_t)(t0+2)*SLAB_V4 + bi];
      u32x4 B2 = h14[(size_t)(t0+3)*SLAB_V4 + bi];
      u32x4 B3 = h14[(size_t)(t0+4)*SLAB_V4 + bi];
      #pragma unroll
      for (int mt = 0; mt < 8; ++mt){
        u32x4 Ah = sA[(s*8 + mt)*128 + l];
        u32x4 Al = sA[(s*8 + mt)*128 + 64 + l];
        MFMA(acc0[mt], Ah, B0); MFMA(acc1[mt], Ah, B1);
        MFMA(acc2[mt], Ah, B2); MFMA(acc3[mt], Ah, B3);
        MFMA(acc0[mt], Al, B0); MFMA(acc1[mt], Al, B1);
        MFMA(acc2[mt], Al, B2); MFMA(acc3[mt], Al, B3);
      }
    }
  }

  // epilogue: per t, transpose C through LDS, add bias, dense stores
  float* sC = (float*)sA;                     // [64][132] fp32 = 33.8 KB
#define EPILOGUE(ACC, TT)                                                       \
  {                                                                             \
    __syncthreads();                                                            \
    _Pragma("unroll")                                                           \
    for (int mt = 0; mt < 8; ++mt){                                             \
      f32x4 a = ACC[mt];                                                        \
      _Pragma("unroll")                                                         \
      for (int r = 0; r < 4; ++r)                                               \
        sC[b*132 + mt*16 + grp*4 + r] = a[r];                                   \
    }                                                                           \
    __syncthreads();                                                            \
    {                                                                           \
      int bb = tid >> 2, q = tid & 3;                                           \
      const float* cp = sC + bb*132 + q*32;                                     \
      const float* bo = b_out + vbase + q*32;                                   \
      float* op = out + ((size_t)(t0+TT)*BATCH + bb)*VOCAB + vbase + q*32;      \
      _Pragma("unroll")                                                         \
      for (int j = 0; j < 8; ++j){                                              \
        float4 cv = *(const float4*)(cp + j*4);                                 \
        float4 bv = *(const float4*)(bo + j*4);                                 \
        float4 ov = {cv.x+bv.x, cv.y+bv.y, cv.z+bv.z, cv.w+bv.w};               \
        *(float4*)(op + j*4) = ov;                                              \
      }                                                                         \
    }                                                                           \
  }
  EPILOGUE(acc0, 0)
  EPILOGUE(acc1, 1)
  EPILOGUE(acc2, 2)
  EPILOGUE(acc3, 3)
#undef EPILOGUE
}

// ---------------------------------------------------------------------------
extern "C" void kernel_launch(void* const* d_in, const int* in_sizes, int n_in,
                              void* d_out, int out_size, void* d_ws, size_t ws_size,
                              hipStream_t stream)
{
  const int*   x     = (const int*)  d_in[0];
  const float* emb   = (const float*)d_in[1];
  const float* W_ih1 = (const float*)d_in[2];
  const float* W_hh1 = (const float*)d_in[3];
  const float* b_ih1 = (const float*)d_in[4];
  const float* b_hh1 = (const float*)d_in[5];
  const float* W_ih2 = (const float*)d_in[6];
  const float* W_hh2 = (const float*)d_in[7];
  const float* b_ih2 = (const float*)d_in[8];
  const float* b_hh2 = (const float*)d_in[9];
  const float* W_out = (const float*)d_in[10];
  const float* b_out = (const float*)d_in[11];
  float* out = (float*)d_out;

  char* ws = (char*)d_ws;
  int*   flags0 = (int*)  (ws + OFF_FLAGS0);
  int*   flags1 = (int*)  (ws + OFF_FLAGS1);
  u16*   h0P    = (u16*)  (ws + OFF_H0);
  u16*   h1P    = (u16*)  (ws + OFF_H1);
  u32x4* xP     = (u32x4*)(ws + OFF_XP);

  hipMemsetAsync(ws + OFF_FLAGS0, 0, 262144, stream);  // both flag arrays
  hipMemsetAsync(ws + OFF_H0, 0, 131072, stream);      // h0 slab 0 = zeros
  hipMemsetAsync(ws + OFF_H1, 0, 131072, stream);      // h1 slab 0 = zeros

  embed_pack<<<4096, 256, 0, stream>>>(x, emb, xP);

  lstm_persist<<<256, 256, 0, stream>>>(
      xP, h0P, h1P, W_ih1, W_hh1, W_ih2, W_hh2,
      b_ih1, b_hh1, b_ih2, b_hh2, flags0, flags1);

  dim3 og(VOCAB/128, TX/4);
  out_gemm<<<og, 256, 0, stream>>>(h1P, W_out, b_out, out);
}

// Round 6
// 1851.517 us; speedup vs baseline: 3.1731x; 1.0635x over previous
//
#include <hip/hip_runtime.h>
#include <math.h>
#include <stdint.h>

#define VOCAB 2048
#define EMB   512
#define HID   1024
#define TX    256
#define BATCH 64

typedef __attribute__((ext_vector_type(8))) short bf16x8;
typedef __attribute__((ext_vector_type(4))) float f32x4;
typedef unsigned int u32;
typedef unsigned short u16;
typedef unsigned long long u64;
typedef __attribute__((ext_vector_type(4))) u32 u32x4;

// ---------------- ws byte offsets ----------------
// cnt0a/cnt0b : [256 t] counters, stride 16 u32 (64B) — L1-done, mirrored
// cnt1        : [256 t] counters — L2-done
// h0P         : 257 slabs of [128 kblk][64 b][8] bf16
// h1P         : 257 slabs (slab 0 zeroed)
// xP          : [TX][64 kblk][64 b][8] bf16
#define OFF_CNT0A 0u
#define OFF_CNT0B 16384u
#define OFF_CNT1  32768u
#define OFF_H0    262144u
#define OFF_H1    33947648u
#define OFF_XP    67633152u
#define SLAB_U16  65536u
#define SLAB_V4   8192u

__device__ __forceinline__ u16 f2bf(float x){
  u32 v = __float_as_uint(x);
  v += 0x7fffu + ((v >> 16) & 1u);          // RNE
  return (u16)(v >> 16);
}
__device__ __forceinline__ u32 pack2(float a, float b){
  return (u32)f2bf(a) | ((u32)f2bf(b) << 16);
}
__device__ __forceinline__ float bf2f(u16 h){ return __uint_as_float(((u32)h) << 16); }
__device__ __forceinline__ float sigm(float x){ return 1.f/(1.f+__expf(-x)); }
__device__ __forceinline__ float tanh_(float x){
  float e = __expf(2.f*fabsf(x));           // overflow-safe
  return copysignf(1.f - 2.f/(e+1.f), x);
}

// ---------------------------------------------------------------------------
__global__ __launch_bounds__(256) void embed_pack(
    const int* __restrict__ x, const float* __restrict__ emb, u32x4* __restrict__ xP)
{
  int flat = blockIdx.x*256 + threadIdx.x;   // t*4096 + kblk*64 + b
  int b    = flat & 63;
  int kblk = (flat >> 6) & 63;
  int t    = flat >> 12;
  int idx  = x[b*TX + t];
  const float* src = emb + (size_t)idx*EMB + kblk*8;
  u32x4 o;
  o.x = pack2(src[0], src[1]);
  o.y = pack2(src[2], src[3]);
  o.z = pack2(src[4], src[5]);
  o.w = pack2(src[6], src[7]);
  xP[flat] = o;
}

// ---------------------------------------------------------------------------
// Layer-specialized persistent LSTM (r5 topology). Publish reworked:
// h repacked via LDS, stored by wave0 as coalesced 16B agent-scope stores;
// done-signal is one fetch_add per block to a per-step aggregate counter;
// detect is a single-lane poll + __syncthreads broadcast. No per-lane
// polling, no same-line atomic storms, no cache maintenance anywhere.
// ---------------------------------------------------------------------------
#define MFMA(ACC, AV, BV)                                                       \
  ACC = __builtin_amdgcn_mfma_f32_16x16x32_bf16(                                \
      *(bf16x8*)&(AV), *(bf16x8*)&(BV), ACC, 0, 0, 0)

__device__ __forceinline__ u32 cell_h(const f32x4& A, const f32x4& B,
                                      const float* bs, float& c){
  float p0=A[0]+B[0]+bs[0], p1=A[1]+B[1]+bs[1];
  float p2=A[2]+B[2]+bs[2], p3=A[3]+B[3]+bs[3];
  float iv=sigm(p0), fv=sigm(p1), gv=tanh_(p2), ov=sigm(p3);
  c = fv*c + iv*gv;
  return (u32)f2bf(ov*tanh_(c));
}

__device__ __forceinline__ void poll_cnt(const int* c, int target){
  if (threadIdx.x == 0)
    while (__hip_atomic_load(c, __ATOMIC_RELAXED, __HIP_MEMORY_SCOPE_AGENT) < target)
      __builtin_amdgcn_s_sleep(1);
  __syncthreads();
}

__global__ __launch_bounds__(256, 1) void lstm_persist(
    const u32x4* __restrict__ xP, u16* __restrict__ h0P, u16* __restrict__ h1P,
    const float* __restrict__ Wih1, const float* __restrict__ Whh1,
    const float* __restrict__ Wih2, const float* __restrict__ Whh2,
    const float* __restrict__ bi1, const float* __restrict__ bh1,
    const float* __restrict__ bi2, const float* __restrict__ bh2,
    int* __restrict__ cnt0a, int* __restrict__ cnt0b, int* __restrict__ cnt1)
{
  __shared__ u32x4 sW[8192];                  // 128 KB
  __shared__ u16   sH[512];                   // 1 KB publish repack
  const int tid = threadIdx.x;
  const int blk = blockIdx.x;
  const bool isL1 = (blk < 128);
  const int  lblk = isL1 ? blk : (blk - 128);

  // ---- pack this block's weight slice fp32 -> bf16 LDS (r5 layout) ----
  {
    const int nsec = isL1 ? 6144 : 8192;
    for (int i = tid; i < nsec; i += 256){
      int m = i & 15, grp_ = (i >> 4) & 3, T = (i >> 6) & 1, s = i >> 7;
      const float* W; int K, ks;
      if (isL1){
        if (s < 16){ W = Wih1; K = 512;  ks = s;      }
        else       { W = Whh1; K = 1024; ks = s - 16; }
      } else {
        if (s < 32){ W = Wih2; K = 1024; ks = s;      }
        else       { W = Whh2; K = 1024; ks = s - 32; }
      }
      int u = m >> 2, r = m & 3;
      const float* src = W + (size_t)(r*HID + lblk*8 + T*4 + u)*K + ks*32 + grp_*8;
      float4 a = *(const float4*)src;
      float4 c = *(const float4*)(src + 4);
      u32x4 o;
      o.x = pack2(a.x, a.y); o.y = pack2(a.z, a.w);
      o.z = pack2(c.x, c.y); o.w = pack2(c.z, c.w);
      sW[i] = o;
    }
  }

  const int w    = tid >> 6, l = tid & 63;
  const int grp  = l >> 4,  col = l & 15;
  const int b    = w*16 + col;
  const int aoff = l;
  const int boff = grp*64 + b;

  const int unitA = lblk*8 + grp;
  const int unitB = lblk*8 + 4 + grp;
  float bsA[4], bsB[4];
  #pragma unroll
  for (int r = 0; r < 4; ++r){
    if (isL1){
      bsA[r] = bi1[r*HID + unitA] + bh1[r*HID + unitA];
      bsB[r] = bi1[r*HID + unitB] + bh1[r*HID + unitB];
    } else {
      bsA[r] = bi2[r*HID + unitA] + bh2[r*HID + unitA];
      bsB[r] = bi2[r*HID + unitB] + bh2[r*HID + unitB];
    }
  }
  float cA = 0.f, cB = 0.f;
  const u32x4* h04 = (const u32x4*)h0P;
  const u32x4* h14 = (const u32x4*)h1P;
  __syncthreads();

  // publish helper (macro to avoid lambda overhead):
  // write m0/m1 -> sH, barrier, wave0 stores 16B/lane agent-scope, barrier,
  // tid0 bumps counters (after wave0's vmcnt(0) drain at the barrier).
#define PUBLISH(DSTP, CADD_A, CADD_B)                                           \
  {                                                                             \
    sH[b*8 + grp]     = (u16)m0;                                                \
    sH[b*8 + 4 + grp] = (u16)m1;                                                \
    __syncthreads();                                                            \
    if (tid < 64){                                                              \
      u32x4 hv = *(const u32x4*)&sH[tid*8];                                     \
      u64* dst = (u64*)((DSTP) + tid*8);                                        \
      u64 lo = ((u64)hv.y << 32) | (u64)hv.x;                                   \
      u64 hi = ((u64)hv.w << 32) | (u64)hv.z;                                   \
      __hip_atomic_store(dst,     lo, __ATOMIC_RELAXED, __HIP_MEMORY_SCOPE_AGENT);\
      __hip_atomic_store(dst + 1, hi, __ATOMIC_RELAXED, __HIP_MEMORY_SCOPE_AGENT);\
    }                                                                           \
    __syncthreads();                                                            \
    if (tid == 0){                                                              \
      __hip_atomic_fetch_add(CADD_A, 1, __ATOMIC_RELAXED, __HIP_MEMORY_SCOPE_AGENT);\
      if (CADD_B)                                                               \
        __hip_atomic_fetch_add((int*)(CADD_B), 1, __ATOMIC_RELAXED,             \
                               __HIP_MEMORY_SCOPE_AGENT);                       \
    }                                                                           \
  }

  if (isL1){
    // ================= LAYER-1 blocks =================
    for (int t = 0; t < TX; ++t){
      f32x4 a00={0,0,0,0}, a01={0,0,0,0}, a10={0,0,0,0}, a11={0,0,0,0};
      // x-part first (overlaps peers' publish propagation)
      {
        const u32x4* Bx = xP + (size_t)t*4096;
        #pragma unroll
        for (int s = 0; s < 16; s += 2){
          u32x4 B0 = Bx[s*256 + boff], B1 = Bx[(s+1)*256 + boff];
          MFMA(a00, sW[(s*2+0)*64 + aoff], B0);
          MFMA(a10, sW[(s*2+1)*64 + aoff], B0);
          MFMA(a01, sW[(s*2+2)*64 + aoff], B1);
          MFMA(a11, sW[(s*2+3)*64 + aoff], B1);
        }
      }
      if (t > 0) poll_cnt(cnt0a + (t-1)*16, 128);
      {
        const u32x4* Bh = h04 + (size_t)t*SLAB_V4;
        #pragma unroll
        for (int s = 0; s < 32; s += 2){
          u32x4 B0 = Bh[s*256 + boff], B1 = Bh[(s+1)*256 + boff];
          MFMA(a00, sW[((16+s)*2+0)*64 + aoff], B0);
          MFMA(a10, sW[((16+s)*2+1)*64 + aoff], B0);
          MFMA(a01, sW[((17+s)*2+0)*64 + aoff], B1);
          MFMA(a11, sW[((17+s)*2+1)*64 + aoff], B1);
        }
      }
      u32 m0 = cell_h(a00, a01, bsA, cA);
      u32 m1 = cell_h(a10, a11, bsB, cB);
      PUBLISH(h0P + (size_t)(t+1)*SLAB_U16 + (lblk<<9),
              cnt0a + t*16, cnt0b + t*16)
    }
  } else {
    // ================= LAYER-2 blocks =================
    for (int t = 0; t < TX; ++t){
      f32x4 a00={0,0,0,0}, a01={0,0,0,0}, a10={0,0,0,0}, a11={0,0,0,0};
      if (t > 0) poll_cnt(cnt1 + (t-1)*16, 128);
      {
        const u32x4* Bh = h14 + (size_t)t*SLAB_V4;
        #pragma unroll
        for (int s = 0; s < 32; s += 2){
          u32x4 B0 = Bh[s*256 + boff], B1 = Bh[(s+1)*256 + boff];
          MFMA(a00, sW[((32+s)*2+0)*64 + aoff], B0);
          MFMA(a10, sW[((32+s)*2+1)*64 + aoff], B0);
          MFMA(a01, sW[((33+s)*2+0)*64 + aoff], B1);
          MFMA(a11, sW[((33+s)*2+1)*64 + aoff], B1);
        }
      }
      poll_cnt(cnt0b + t*16, 128);
      {
        const u32x4* Bh = h04 + (size_t)(t+1)*SLAB_V4;
        #pragma unroll
        for (int s = 0; s < 32; s += 2){
          u32x4 B0 = Bh[s*256 + boff], B1 = Bh[(s+1)*256 + boff];
          MFMA(a00, sW[(s*2+0)*64 + aoff], B0);
          MFMA(a10, sW[(s*2+1)*64 + aoff], B0);
          MFMA(a01, sW[((s+1)*2+0)*64 + aoff], B1);
          MFMA(a11, sW[((s+1)*2+1)*64 + aoff], B1);
        }
      }
      u32 m0 = cell_h(a00, a01, bsA, cA);
      u32 m1 = cell_h(a10, a11, bsB, cB);
      PUBLISH(h1P + (size_t)(t+1)*SLAB_U16 + (lblk<<9),
              cnt1 + t*16, (int*)0)
    }
  }
#undef PUBLISH
}

// ---------------------------------------------------------------------------
// MFMA output projection with split-precision W_out (bf16 hi + bf16 lo).
// (unchanged from round 5)
// ---------------------------------------------------------------------------
__global__ __launch_bounds__(256, 1) void out_gemm(
    const u16* __restrict__ h1P, const float* __restrict__ W_out,
    const float* __restrict__ b_out, float* __restrict__ out)
{
  __shared__ u32x4 sA[8192];                  // 128 KB (A hi/lo chunk; C reuse)
  const int tid = threadIdx.x, l = tid & 63, w = tid >> 6;
  const int grp = l >> 4, col = l & 15;
  const int b   = w*16 + col;
  const int vbase = blockIdx.x * 128;
  const int t0    = blockIdx.y * 4;

  f32x4 acc0[8], acc1[8], acc2[8], acc3[8];
  #pragma unroll
  for (int m = 0; m < 8; ++m){
    acc0[m]=(f32x4){0,0,0,0}; acc1[m]=(f32x4){0,0,0,0};
    acc2[m]=(f32x4){0,0,0,0}; acc3[m]=(f32x4){0,0,0,0};
  }
  const u32x4* h14 = (const u32x4*)h1P;

  for (int kc = 0; kc < 4; ++kc){
    __syncthreads();
    #pragma unroll
    for (int k = 0; k < 16; ++k){
      int j = tid + k*256;
      int lane = j & 63, mt = (j >> 6) & 7, s = j >> 9;
      int v  = vbase + mt*16 + (lane & 15);
      int kk = kc*256 + s*32 + (lane >> 4)*8;
      const float* src = W_out + (size_t)v*HID + kk;
      float4 f0 = *(const float4*)src, f1 = *(const float4*)(src + 4);
      float e[8] = {f0.x,f0.y,f0.z,f0.w,f1.x,f1.y,f1.z,f1.w};
      u16 hi[8]; float lo[8];
      #pragma unroll
      for (int r = 0; r < 8; ++r){ hi[r] = f2bf(e[r]); lo[r] = e[r] - bf2f(hi[r]); }
      u32x4 H, L;
      H.x = (u32)hi[0]|((u32)hi[1]<<16); H.y = (u32)hi[2]|((u32)hi[3]<<16);
      H.z = (u32)hi[4]|((u32)hi[5]<<16); H.w = (u32)hi[6]|((u32)hi[7]<<16);
      L.x = pack2(lo[0],lo[1]); L.y = pack2(lo[2],lo[3]);
      L.z = pack2(lo[4],lo[5]); L.w = pack2(lo[6],lo[7]);
      int base = (s*8 + mt)*128 + lane;
      sA[base]      = H;
      sA[base + 64] = L;
    }
    __syncthreads();

    #pragma unroll
    for (int s = 0; s < 8; ++s){
      int ksl = kc*8 + s;
      int bi  = ksl*256 + grp*64 + b;
      u32x4 B0 = h14[(size_t)(t0+1)*SLAB_V4 + bi];
      u32x4 B1 = h14[(size_t)(t0+2)*SLAB_V4 + bi];
      u32x4 B2 = h14[(size_t)(t0+3)*SLAB_V4 + bi];
      u32x4 B3 = h14[(size_t)(t0+4)*SLAB_V4 + bi];
      #pragma unroll
      for (int mt = 0; mt < 8; ++mt){
        u32x4 Ah = sA[(s*8 + mt)*128 + l];
        u32x4 Al = sA[(s*8 + mt)*128 + 64 + l];
        MFMA(acc0[mt], Ah, B0); MFMA(acc1[mt], Ah, B1);
        MFMA(acc2[mt], Ah, B2); MFMA(acc3[mt], Ah, B3);
        MFMA(acc0[mt], Al, B0); MFMA(acc1[mt], Al, B1);
        MFMA(acc2[mt], Al, B2); MFMA(acc3[mt], Al, B3);
      }
    }
  }

  float* sC = (float*)sA;                     // [64][132] fp32
#define EPILOGUE(ACC, TT)                                                       \
  {                                                                             \
    __syncthreads();                                                            \
    _Pragma("unroll")                                                           \
    for (int mt = 0; mt < 8; ++mt){                                             \
      f32x4 a = ACC[mt];                                                        \
      _Pragma("unroll")                                                         \
      for (int r = 0; r < 4; ++r)                                               \
        sC[b*132 + mt*16 + grp*4 + r] = a[r];                                   \
    }                                                                           \
    __syncthreads();                                                            \
    {                                                                           \
      int bb = tid >> 2, q = tid & 3;                                           \
      const float* cp = sC + bb*132 + q*32;                                     \
      const float* bo = b_out + vbase + q*32;                                   \
      float* op = out + ((size_t)(t0+TT)*BATCH + bb)*VOCAB + vbase + q*32;      \
      _Pragma("unroll")                                                         \
      for (int j = 0; j < 8; ++j){                                              \
        float4 cv = *(const float4*)(cp + j*4);                                 \
        float4 bv = *(const float4*)(bo + j*4);                                 \
        float4 ov = {cv.x+bv.x, cv.y+bv.y, cv.z+bv.z, cv.w+bv.w};               \
        *(float4*)(op + j*4) = ov;                                              \
      }                                                                         \
    }                                                                           \
  }
  EPILOGUE(acc0, 0)
  EPILOGUE(acc1, 1)
  EPILOGUE(acc2, 2)
  EPILOGUE(acc3, 3)
#undef EPILOGUE
}

// ---------------------------------------------------------------------------
extern "C" void kernel_launch(void* const* d_in, const int* in_sizes, int n_in,
                              void* d_out, int out_size, void* d_ws, size_t ws_size,
                              hipStream_t stream)
{
  const int*   x     = (const int*)  d_in[0];
  const float* emb   = (const float*)d_in[1];
  const float* W_ih1 = (const float*)d_in[2];
  const float* W_hh1 = (const float*)d_in[3];
  const float* b_ih1 = (const float*)d_in[4];
  const float* b_hh1 = (const float*)d_in[5];
  const float* W_ih2 = (const float*)d_in[6];
  const float* W_hh2 = (const float*)d_in[7];
  const float* b_ih2 = (const float*)d_in[8];
  const float* b_hh2 = (const float*)d_in[9];
  const float* W_out = (const float*)d_in[10];
  const float* b_out = (const float*)d_in[11];
  float* out = (float*)d_out;

  char* ws = (char*)d_ws;
  int*   cnt0a = (int*)  (ws + OFF_CNT0A);
  int*   cnt0b = (int*)  (ws + OFF_CNT0B);
  int*   cnt1  = (int*)  (ws + OFF_CNT1);
  u16*   h0P   = (u16*)  (ws + OFF_H0);
  u16*   h1P   = (u16*)  (ws + OFF_H1);
  u32x4* xP    = (u32x4*)(ws + OFF_XP);

  hipMemsetAsync(ws, 0, 262144, stream);               // all counters
  hipMemsetAsync(ws + OFF_H0, 0, 131072, stream);      // h0 slab 0 = zeros
  hipMemsetAsync(ws + OFF_H1, 0, 131072, stream);      // h1 slab 0 = zeros

  embed_pack<<<4096, 256, 0, stream>>>(x, emb, xP);

  lstm_persist<<<256, 256, 0, stream>>>(
      xP, h0P, h1P, W_ih1, W_hh1, W_ih2, W_hh2,
      b_ih1, b_hh1, b_ih2, b_hh2, cnt0a, cnt0b, cnt1);

  dim3 og(VOCAB/128, TX/4);
  out_gemm<<<og, 256, 0, stream>>>(h1P, W_out, b_out, out);
}

// Round 7
// 1537.691 us; speedup vs baseline: 3.8206x; 1.2041x over previous
//
#include <hip/hip_runtime.h>
#include <math.h>
#include <stdint.h>

#define VOCAB 2048
#define EMB   512
#define HID   1024
#define TX    256
#define BATCH 64

typedef __attribute__((ext_vector_type(8))) short bf16x8;
typedef __attribute__((ext_vector_type(4))) float f32x4;
typedef unsigned int u32;
typedef unsigned short u16;
typedef unsigned long long u64;
typedef __attribute__((ext_vector_type(4))) u32 u32x4;

// ---------------- ws byte offsets ----------------
// cnt0a/cnt0b/cnt1 : [256 t][8 shard x 128B] counters (memset 0 per launch)
//   shard s collects 16 producer adds; consumers poll all 8 shards.
// h0P : 257 slabs of [128 kblk][64 b][8] bf16  (slab t+1 = h0 after step t)
// h1P : 257 slabs (slab 0 zeroed)
// xP  : [TX][64 kblk][64 b][8] bf16
#define OFF_CNT0A 0u
#define OFF_CNT0B 262144u
#define OFF_CNT1  524288u
#define OFF_H0    1048576u
#define OFF_H1    34734080u
#define OFF_XP    68419584u
#define SLAB_U16  65536u
#define SLAB_V4   8192u

__device__ __forceinline__ u16 f2bf(float x){
  u32 v = __float_as_uint(x);
  v += 0x7fffu + ((v >> 16) & 1u);          // RNE
  return (u16)(v >> 16);
}
__device__ __forceinline__ u32 pack2(float a, float b){
  return (u32)f2bf(a) | ((u32)f2bf(b) << 16);
}
__device__ __forceinline__ float bf2f(u16 h){ return __uint_as_float(((u32)h) << 16); }
__device__ __forceinline__ float sigm(float x){ return 1.f/(1.f+__expf(-x)); }
__device__ __forceinline__ float tanh_(float x){
  float e = __expf(2.f*fabsf(x));           // overflow-safe
  return copysignf(1.f - 2.f/(e+1.f), x);
}

// ---------------------------------------------------------------------------
__global__ __launch_bounds__(256) void embed_pack(
    const int* __restrict__ x, const float* __restrict__ emb, u32x4* __restrict__ xP)
{
  int flat = blockIdx.x*256 + threadIdx.x;   // t*4096 + kblk*64 + b
  int b    = flat & 63;
  int kblk = (flat >> 6) & 63;
  int t    = flat >> 12;
  int idx  = x[b*TX + t];
  const float* src = emb + (size_t)idx*EMB + kblk*8;
  u32x4 o;
  o.x = pack2(src[0], src[1]);
  o.y = pack2(src[2], src[3]);
  o.z = pack2(src[4], src[5]);
  o.w = pack2(src[6], src[7]);
  xP[flat] = o;
}

// ---------------------------------------------------------------------------
// Layer-specialized persistent LSTM. Blocks 0..127 = L1, 128..255 = L2.
// v7: (1) L2 computes the h0-part FIRST (L1 runs ahead -> its poll is free),
// hiding L2's own-group publish->detect hop under the h0 slab read + MFMAs.
// (2) counters sharded 8x (128B stride) to cut same-line RMW serialization.
// (3) publish: sH double-buffered (one barrier) + wave0-local vmcnt(0) drain
// before the counter bump (no second block barrier).
// ---------------------------------------------------------------------------
#define MFMA(ACC, AV, BV)                                                       \
  ACC = __builtin_amdgcn_mfma_f32_16x16x32_bf16(                                \
      *(bf16x8*)&(AV), *(bf16x8*)&(BV), ACC, 0, 0, 0)

__device__ __forceinline__ u32 cell_h(const f32x4& A, const f32x4& B,
                                      const float* bs, float& c){
  float p0=A[0]+B[0]+bs[0], p1=A[1]+B[1]+bs[1];
  float p2=A[2]+B[2]+bs[2], p3=A[3]+B[3]+bs[3];
  float iv=sigm(p0), fv=sigm(p1), gv=tanh_(p2), ov=sigm(p3);
  c = fv*c + iv*gv;
  return (u32)f2bf(ov*tanh_(c));
}

__device__ __forceinline__ void poll8(const int* base){
  if (threadIdx.x < 8){
    const int* c = base + threadIdx.x*32;      // 128B-strided shard
    while (__hip_atomic_load(c, __ATOMIC_RELAXED, __HIP_MEMORY_SCOPE_AGENT) < 16)
      __builtin_amdgcn_s_sleep(1);
  }
  __syncthreads();
}

__global__ __launch_bounds__(256, 1) void lstm_persist(
    const u32x4* __restrict__ xP, u16* __restrict__ h0P, u16* __restrict__ h1P,
    const float* __restrict__ Wih1, const float* __restrict__ Whh1,
    const float* __restrict__ Wih2, const float* __restrict__ Whh2,
    const float* __restrict__ bi1, const float* __restrict__ bh1,
    const float* __restrict__ bi2, const float* __restrict__ bh2,
    int* __restrict__ cnt0a, int* __restrict__ cnt0b, int* __restrict__ cnt1)
{
  __shared__ u32x4 sW[8192];                  // 128 KB
  __shared__ u16   sH[2][512];                // double-buffered publish repack
  const int tid = threadIdx.x;
  const int blk = blockIdx.x;
  const bool isL1 = (blk < 128);
  const int  lblk = isL1 ? blk : (blk - 128);
  const int  shard = lblk & 7;

  // ---- pack this block's weight slice fp32 -> bf16 LDS (r5/r6 layout) ----
  {
    const int nsec = isL1 ? 6144 : 8192;
    for (int i = tid; i < nsec; i += 256){
      int m = i & 15, grp_ = (i >> 4) & 3, T = (i >> 6) & 1, s = i >> 7;
      const float* W; int K, ks;
      if (isL1){
        if (s < 16){ W = Wih1; K = 512;  ks = s;      }
        else       { W = Whh1; K = 1024; ks = s - 16; }
      } else {
        if (s < 32){ W = Wih2; K = 1024; ks = s;      }
        else       { W = Whh2; K = 1024; ks = s - 32; }
      }
      int u = m >> 2, r = m & 3;
      const float* src = W + (size_t)(r*HID + lblk*8 + T*4 + u)*K + ks*32 + grp_*8;
      float4 a = *(const float4*)src;
      float4 c = *(const float4*)(src + 4);
      u32x4 o;
      o.x = pack2(a.x, a.y); o.y = pack2(a.z, a.w);
      o.z = pack2(c.x, c.y); o.w = pack2(c.z, c.w);
      sW[i] = o;
    }
  }

  const int w    = tid >> 6, l = tid & 63;
  const int grp  = l >> 4,  col = l & 15;
  const int b    = w*16 + col;
  const int aoff = l;
  const int boff = grp*64 + b;

  const int unitA = lblk*8 + grp;
  const int unitB = lblk*8 + 4 + grp;
  float bsA[4], bsB[4];
  #pragma unroll
  for (int r = 0; r < 4; ++r){
    if (isL1){
      bsA[r] = bi1[r*HID + unitA] + bh1[r*HID + unitA];
      bsB[r] = bi1[r*HID + unitB] + bh1[r*HID + unitB];
    } else {
      bsA[r] = bi2[r*HID + unitA] + bh2[r*HID + unitA];
      bsB[r] = bi2[r*HID + unitB] + bh2[r*HID + unitB];
    }
  }
  float cA = 0.f, cB = 0.f;
  const u32x4* h04 = (const u32x4*)h0P;
  const u32x4* h14 = (const u32x4*)h1P;
  __syncthreads();

  // publish: sH[par] write -> barrier -> wave0: 16B/lane agent stores,
  // wave-local vmcnt(0) drain, lane0 bumps shard counters.
#define PUBLISH(PAR, DSTP, ADD1P, ADD2P)                                        \
  {                                                                             \
    sH[PAR][b*8 + grp]     = (u16)m0;                                           \
    sH[PAR][b*8 + 4 + grp] = (u16)m1;                                           \
    __syncthreads();                                                            \
    if (tid < 64){                                                              \
      u32x4 hv = *(const u32x4*)&sH[PAR][tid*8];                                \
      u64* dst = (u64*)((DSTP) + tid*8);                                        \
      u64 lo = ((u64)hv.y << 32) | (u64)hv.x;                                   \
      u64 hi = ((u64)hv.w << 32) | (u64)hv.z;                                   \
      __hip_atomic_store(dst,     lo, __ATOMIC_RELAXED, __HIP_MEMORY_SCOPE_AGENT);\
      __hip_atomic_store(dst + 1, hi, __ATOMIC_RELAXED, __HIP_MEMORY_SCOPE_AGENT);\
      asm volatile("s_waitcnt vmcnt(0)" ::: "memory");                          \
      if (tid == 0){                                                            \
        __hip_atomic_fetch_add((int*)(ADD1P), 1, __ATOMIC_RELAXED,              \
                               __HIP_MEMORY_SCOPE_AGENT);                       \
        if (ADD2P)                                                              \
          __hip_atomic_fetch_add((int*)(ADD2P), 1, __ATOMIC_RELAXED,            \
                                 __HIP_MEMORY_SCOPE_AGENT);                     \
      }                                                                         \
    }                                                                           \
  }

  if (isL1){
    // ================= LAYER-1 blocks =================
    for (int t = 0; t < TX; ++t){
      f32x4 a00={0,0,0,0}, a01={0,0,0,0}, a10={0,0,0,0}, a11={0,0,0,0};
      // x-part first: cover for own-hop propagation
      {
        const u32x4* Bx = xP + (size_t)t*4096;
        #pragma unroll
        for (int s = 0; s < 16; s += 2){
          u32x4 B0 = Bx[s*256 + boff], B1 = Bx[(s+1)*256 + boff];
          MFMA(a00, sW[(s*2+0)*64 + aoff], B0);
          MFMA(a10, sW[(s*2+1)*64 + aoff], B0);
          MFMA(a01, sW[(s*2+2)*64 + aoff], B1);
          MFMA(a11, sW[(s*2+3)*64 + aoff], B1);
        }
      }
      if (t > 0) poll8(cnt0a + (t-1)*256);
      {
        const u32x4* Bh = h04 + (size_t)t*SLAB_V4;
        #pragma unroll
        for (int s = 0; s < 32; s += 2){
          u32x4 B0 = Bh[s*256 + boff], B1 = Bh[(s+1)*256 + boff];
          MFMA(a00, sW[((16+s)*2+0)*64 + aoff], B0);
          MFMA(a10, sW[((16+s)*2+1)*64 + aoff], B0);
          MFMA(a01, sW[((17+s)*2+0)*64 + aoff], B1);
          MFMA(a11, sW[((17+s)*2+1)*64 + aoff], B1);
        }
      }
      u32 m0 = cell_h(a00, a01, bsA, cA);
      u32 m1 = cell_h(a10, a11, bsB, cB);
      PUBLISH(t & 1, h0P + (size_t)(t+1)*SLAB_U16 + (lblk<<9),
              cnt0b + t*256 + shard*32,    // L2 consumers first
              cnt0a + t*256 + shard*32)
    }
  } else {
    // ================= LAYER-2 blocks =================
    for (int t = 0; t < TX; ++t){
      f32x4 a00={0,0,0,0}, a01={0,0,0,0}, a10={0,0,0,0}, a11={0,0,0,0};
      // h0-part FIRST: L1 runs ahead, this poll is (nearly) free
      poll8(cnt0b + t*256);
      {
        const u32x4* Bh = h04 + (size_t)(t+1)*SLAB_V4;
        #pragma unroll
        for (int s = 0; s < 32; s += 2){
          u32x4 B0 = Bh[s*256 + boff], B1 = Bh[(s+1)*256 + boff];
          MFMA(a00, sW[(s*2+0)*64 + aoff], B0);
          MFMA(a10, sW[(s*2+1)*64 + aoff], B0);
          MFMA(a01, sW[((s+1)*2+0)*64 + aoff], B1);
          MFMA(a11, sW[((s+1)*2+1)*64 + aoff], B1);
        }
      }
      // own-group hop had the whole h0-part to propagate
      if (t > 0) poll8(cnt1 + (t-1)*256);
      {
        const u32x4* Bh = h14 + (size_t)t*SLAB_V4;
        #pragma unroll
        for (int s = 0; s < 32; s += 2){
          u32x4 B0 = Bh[s*256 + boff], B1 = Bh[(s+1)*256 + boff];
          MFMA(a00, sW[((32+s)*2+0)*64 + aoff], B0);
          MFMA(a10, sW[((32+s)*2+1)*64 + aoff], B0);
          MFMA(a01, sW[((33+s)*2+0)*64 + aoff], B1);
          MFMA(a11, sW[((33+s)*2+1)*64 + aoff], B1);
        }
      }
      u32 m0 = cell_h(a00, a01, bsA, cA);
      u32 m1 = cell_h(a10, a11, bsB, cB);
      PUBLISH(t & 1, h1P + (size_t)(t+1)*SLAB_U16 + (lblk<<9),
              cnt1 + t*256 + shard*32, (int*)0)
    }
  }
#undef PUBLISH
}

// ---------------------------------------------------------------------------
// MFMA output projection with split-precision W_out (bf16 hi + bf16 lo).
// (unchanged from round 5/6)
// ---------------------------------------------------------------------------
__global__ __launch_bounds__(256, 1) void out_gemm(
    const u16* __restrict__ h1P, const float* __restrict__ W_out,
    const float* __restrict__ b_out, float* __restrict__ out)
{
  __shared__ u32x4 sA[8192];                  // 128 KB (A hi/lo chunk; C reuse)
  const int tid = threadIdx.x, l = tid & 63, w = tid >> 6;
  const int grp = l >> 4, col = l & 15;
  const int b   = w*16 + col;
  const int vbase = blockIdx.x * 128;
  const int t0    = blockIdx.y * 4;

  f32x4 acc0[8], acc1[8], acc2[8], acc3[8];
  #pragma unroll
  for (int m = 0; m < 8; ++m){
    acc0[m]=(f32x4){0,0,0,0}; acc1[m]=(f32x4){0,0,0,0};
    acc2[m]=(f32x4){0,0,0,0}; acc3[m]=(f32x4){0,0,0,0};
  }
  const u32x4* h14 = (const u32x4*)h1P;

  for (int kc = 0; kc < 4; ++kc){
    __syncthreads();
    #pragma unroll
    for (int k = 0; k < 16; ++k){
      int j = tid + k*256;
      int lane = j & 63, mt = (j >> 6) & 7, s = j >> 9;
      int v  = vbase + mt*16 + (lane & 15);
      int kk = kc*256 + s*32 + (lane >> 4)*8;
      const float* src = W_out + (size_t)v*HID + kk;
      float4 f0 = *(const float4*)src, f1 = *(const float4*)(src + 4);
      float e[8] = {f0.x,f0.y,f0.z,f0.w,f1.x,f1.y,f1.z,f1.w};
      u16 hi[8]; float lo[8];
      #pragma unroll
      for (int r = 0; r < 8; ++r){ hi[r] = f2bf(e[r]); lo[r] = e[r] - bf2f(hi[r]); }
      u32x4 H, L;
      H.x = (u32)hi[0]|((u32)hi[1]<<16); H.y = (u32)hi[2]|((u32)hi[3]<<16);
      H.z = (u32)hi[4]|((u32)hi[5]<<16); H.w = (u32)hi[6]|((u32)hi[7]<<16);
      L.x = pack2(lo[0],lo[1]); L.y = pack2(lo[2],lo[3]);
      L.z = pack2(lo[4],lo[5]); L.w = pack2(lo[6],lo[7]);
      int base = (s*8 + mt)*128 + lane;
      sA[base]      = H;
      sA[base + 64] = L;
    }
    __syncthreads();

    #pragma unroll
    for (int s = 0; s < 8; ++s){
      int ksl = kc*8 + s;
      int bi  = ksl*256 + grp*64 + b;
      u32x4 B0 = h14[(size_t)(t0+1)*SLAB_V4 + bi];
      u32x4 B1 = h14[(size_t)(t0+2)*SLAB_V4 + bi];
      u32x4 B2 = h14[(size_t)(t0+3)*SLAB_V4 + bi];
      u32x4 B3 = h14[(size_t)(t0+4)*SLAB_V4 + bi];
      #pragma unroll
      for (int mt = 0; mt < 8; ++mt){
        u32x4 Ah = sA[(s*8 + mt)*128 + l];
        u32x4 Al = sA[(s*8 + mt)*128 + 64 + l];
        MFMA(acc0[mt], Ah, B0); MFMA(acc1[mt], Ah, B1);
        MFMA(acc2[mt], Ah, B2); MFMA(acc3[mt], Ah, B3);
        MFMA(acc0[mt], Al, B0); MFMA(acc1[mt], Al, B1);
        MFMA(acc2[mt], Al, B2); MFMA(acc3[mt], Al, B3);
      }
    }
  }

  float* sC = (float*)sA;                     // [64][132] fp32
#define EPILOGUE(ACC, TT)                                                       \
  {                                                                             \
    __syncthreads();                                                            \
    _Pragma("unroll")                                                           \
    for (int mt = 0; mt < 8; ++mt){                                             \
      f32x4 a = ACC[mt];                                                        \
      _Pragma("unroll")                                                         \
      for (int r = 0; r < 4; ++r)                                               \
        sC[b*132 + mt*16 + grp*4 + r] = a[r];                                   \
    }                                                                           \
    __syncthreads();                                                            \
    {                                                                           \
      int bb = tid >> 2, q = tid & 3;                                           \
      const float* cp = sC + bb*132 + q*32;                                     \
      const float* bo = b_out + vbase + q*32;                                   \
      float* op = out + ((size_t)(t0+TT)*BATCH + bb)*VOCAB + vbase + q*32;      \
      _Pragma("unroll")                                                         \
      for (int j = 0; j < 8; ++j){                                              \
        float4 cv = *(const float4*)(cp + j*4);                                 \
        float4 bv = *(const float4*)(bo + j*4);                                 \
        float4 ov = {cv.x+bv.x, cv.y+bv.y, cv.z+bv.z, cv.w+bv.w};               \
        *(float4*)(op + j*4) = ov;                                              \
      }                                                                         \
    }                                                                           \
  }
  EPILOGUE(acc0, 0)
  EPILOGUE(acc1, 1)
  EPILOGUE(acc2, 2)
  EPILOGUE(acc3, 3)
#undef EPILOGUE
}

// ---------------------------------------------------------------------------
extern "C" void kernel_launch(void* const* d_in, const int* in_sizes, int n_in,
                              void* d_out, int out_size, void* d_ws, size_t ws_size,
                              hipStream_t stream)
{
  const int*   x     = (const int*)  d_in[0];
  const float* emb   = (const float*)d_in[1];
  const float* W_ih1 = (const float*)d_in[2];
  const float* W_hh1 = (const float*)d_in[3];
  const float* b_ih1 = (const float*)d_in[4];
  const float* b_hh1 = (const float*)d_in[5];
  const float* W_ih2 = (const float*)d_in[6];
  const float* W_hh2 = (const float*)d_in[7];
  const float* b_ih2 = (const float*)d_in[8];
  const float* b_hh2 = (const float*)d_in[9];
  const float* W_out = (const float*)d_in[10];
  const float* b_out = (const float*)d_in[11];
  float* out = (float*)d_out;

  char* ws = (char*)d_ws;
  int*   cnt0a = (int*)  (ws + OFF_CNT0A);
  int*   cnt0b = (int*)  (ws + OFF_CNT0B);
  int*   cnt1  = (int*)  (ws + OFF_CNT1);
  u16*   h0P   = (u16*)  (ws + OFF_H0);
  u16*   h1P   = (u16*)  (ws + OFF_H1);
  u32x4* xP    = (u32x4*)(ws + OFF_XP);

  hipMemsetAsync(ws, 0, 786432, stream);               // all counter shards
  hipMemsetAsync(ws + OFF_H0, 0, 131072, stream);      // h0 slab 0 = zeros
  hipMemsetAsync(ws + OFF_H1, 0, 131072, stream);      // h1 slab 0 = zeros

  embed_pack<<<4096, 256, 0, stream>>>(x, emb, xP);

  lstm_persist<<<256, 256, 0, stream>>>(
      xP, h0P, h1P, W_ih1, W_hh1, W_ih2, W_hh2,
      b_ih1, b_hh1, b_ih2, b_hh2, cnt0a, cnt0b, cnt1);

  dim3 og(VOCAB/128, TX/4);
  out_gemm<<<og, 256, 0, stream>>>(h1P, W_out, b_out, out);
}

// Round 8
// 1425.059 us; speedup vs baseline: 4.1226x; 1.0790x over previous
//
#include <hip/hip_runtime.h>
#include <math.h>
#include <stdint.h>

#define VOCAB 2048
#define EMB   512
#define HID   1024
#define TX    256
#define BATCH 64

typedef __attribute__((ext_vector_type(8))) short bf16x8;
typedef __attribute__((ext_vector_type(4))) float f32x4;
typedef unsigned int u32;
typedef unsigned short u16;
typedef unsigned long long u64;
typedef __attribute__((ext_vector_type(4))) u32 u32x4;

// ---------------- ws byte offsets ----------------
// cnt0a/cnt0b/cnt1 : [256 t][4 wave][8 shard] counters, 128B-strided words.
//   producer wave w of block lblk bumps (t, w, lblk&7); target count 16.
// h0P : 257 slabs of [128 kblk][64 b][8] bf16  (slab t+1 = h0 after step t)
// h1P : 257 slabs (slab 0 zeroed)
// xP  : [TX][64 kblk][64 b][8] bf16
#define OFF_CNT0A 0u
#define OFF_CNT0B 1048576u
#define OFF_CNT1  2097152u
#define OFF_H0    3145728u
#define OFF_H1    36831232u
#define OFF_XP    70516736u
#define SLAB_U16  65536u
#define SLAB_V4   8192u

__device__ __forceinline__ u16 f2bf(float x){
  u32 v = __float_as_uint(x);
  v += 0x7fffu + ((v >> 16) & 1u);          // RNE
  return (u16)(v >> 16);
}
__device__ __forceinline__ u32 pack2(float a, float b){
  return (u32)f2bf(a) | ((u32)f2bf(b) << 16);
}
__device__ __forceinline__ float bf2f(u16 h){ return __uint_as_float(((u32)h) << 16); }
__device__ __forceinline__ float sigm(float x){ return 1.f/(1.f+__expf(-x)); }
__device__ __forceinline__ float tanh_(float x){
  float e = __expf(2.f*fabsf(x));           // overflow-safe
  return copysignf(1.f - 2.f/(e+1.f), x);
}

// ---------------------------------------------------------------------------
__global__ __launch_bounds__(256) void embed_pack(
    const int* __restrict__ x, const float* __restrict__ emb, u32x4* __restrict__ xP)
{
  int flat = blockIdx.x*256 + threadIdx.x;   // t*4096 + kblk*64 + b
  int b    = flat & 63;
  int kblk = (flat >> 6) & 63;
  int t    = flat >> 12;
  int idx  = x[b*TX + t];
  const float* src = emb + (size_t)idx*EMB + kblk*8;
  u32x4 o;
  o.x = pack2(src[0], src[1]);
  o.y = pack2(src[2], src[3]);
  o.z = pack2(src[4], src[5]);
  o.w = pack2(src[6], src[7]);
  xP[flat] = o;
}

// ---------------------------------------------------------------------------
// Layer-specialized persistent LSTM, wave-decoupled (v8). Blocks 0..127 = L1,
// 128..255 = L2; block owns 8 units, weights bf16 in LDS. Each wave w handles
// batches 16w..16w+15 end-to-end; producer wave w's output is consumed ONLY
// by consumer waves w (B-frag columns = own batch slice), so sync is
// per-(t,wave,shard) counters and the t-loop has ZERO block barriers.
// Publish: in-wave shfl 4x16 transpose -> 16 lanes x 16B agent-scope stores
// -> wave-local vmcnt(0) -> lane0 fire-and-forget fetch_add.
// ---------------------------------------------------------------------------
#define MFMA(ACC, AV, BV)                                                       \
  ACC = __builtin_amdgcn_mfma_f32_16x16x32_bf16(                                \
      *(bf16x8*)&(AV), *(bf16x8*)&(BV), ACC, 0, 0, 0)

__device__ __forceinline__ u32 cell_h(const f32x4& A, const f32x4& B,
                                      const float* bs, float& c){
  float p0=A[0]+B[0]+bs[0], p1=A[1]+B[1]+bs[1];
  float p2=A[2]+B[2]+bs[2], p3=A[3]+B[3]+bs[3];
  float iv=sigm(p0), fv=sigm(p1), gv=tanh_(p2), ov=sigm(p3);
  c = fv*c + iv*gv;
  return (u32)f2bf(ov*tanh_(c));
}

// wave-level poll: lanes 0..7 watch the 8 shard words, all lanes spin on __all
__device__ __forceinline__ void pollw(const int* base){
  const int l = threadIdx.x & 63;
  const int* c = base + (l & 7)*32;          // 128B-strided shard words
  const bool mine = (l < 8);
  for (;;){
    int v = mine ? __hip_atomic_load(c, __ATOMIC_RELAXED, __HIP_MEMORY_SCOPE_AGENT)
                 : 16;
    if (__all(v >= 16)) break;
    __builtin_amdgcn_s_sleep(1);
  }
  asm volatile("" ::: "memory");             // no hoisting of slab loads above
}

// in-wave transpose + 16B stores (lanes 0..15); no LDS, no barrier
__device__ __forceinline__ void pub_store(u16* dstp, u32 m0, u32 m1){
  const int l = threadIdx.x & 63;
  u32 p = m0 | (m1 << 16);
  int col = l & 15;
  u32 q0 = (u32)__shfl((int)p, col);
  u32 q1 = (u32)__shfl((int)p, col + 16);
  u32 q2 = (u32)__shfl((int)p, col + 32);
  u32 q3 = (u32)__shfl((int)p, col + 48);
  if (l < 16){
    u64 lo = ((u64)((q2 & 0xffffu) | (q3 << 16)) << 32)
           |  (u64)((q0 & 0xffffu) | (q1 << 16));
    u64 hi = ((u64)((q2 >> 16) | (q3 & 0xffff0000u)) << 32)
           |  (u64)((q0 >> 16) | (q1 & 0xffff0000u));
    u64* dst = (u64*)(dstp + (size_t)l*8);
    __hip_atomic_store(dst,     lo, __ATOMIC_RELAXED, __HIP_MEMORY_SCOPE_AGENT);
    __hip_atomic_store(dst + 1, hi, __ATOMIC_RELAXED, __HIP_MEMORY_SCOPE_AGENT);
  }
}

__device__ __forceinline__ void pub_signal(int* add1, int* add2){
  asm volatile("s_waitcnt vmcnt(0)" ::: "memory");   // wave-local drain
  if ((threadIdx.x & 63) == 0){
    __hip_atomic_fetch_add(add1, 1, __ATOMIC_RELAXED, __HIP_MEMORY_SCOPE_AGENT);
    if (add2)
      __hip_atomic_fetch_add(add2, 1, __ATOMIC_RELAXED, __HIP_MEMORY_SCOPE_AGENT);
  }
}

__global__ __launch_bounds__(256, 1) void lstm_persist(
    const u32x4* __restrict__ xP, u16* __restrict__ h0P, u16* __restrict__ h1P,
    const float* __restrict__ Wih1, const float* __restrict__ Whh1,
    const float* __restrict__ Wih2, const float* __restrict__ Whh2,
    const float* __restrict__ bi1, const float* __restrict__ bh1,
    const float* __restrict__ bi2, const float* __restrict__ bh2,
    int* __restrict__ cnt0a, int* __restrict__ cnt0b, int* __restrict__ cnt1)
{
  __shared__ u32x4 sW[8192];                  // 128 KB
  const int tid = threadIdx.x;
  const int blk = blockIdx.x;
  const bool isL1 = (blk < 128);
  const int  lblk = isL1 ? blk : (blk - 128);
  const int  shard = lblk & 7;

  // ---- pack this block's weight slice fp32 -> bf16 LDS (r5-r7 layout) ----
  {
    const int nsec = isL1 ? 6144 : 8192;
    for (int i = tid; i < nsec; i += 256){
      int m = i & 15, grp_ = (i >> 4) & 3, T = (i >> 6) & 1, s = i >> 7;
      const float* W; int K, ks;
      if (isL1){
        if (s < 16){ W = Wih1; K = 512;  ks = s;      }
        else       { W = Whh1; K = 1024; ks = s - 16; }
      } else {
        if (s < 32){ W = Wih2; K = 1024; ks = s;      }
        else       { W = Whh2; K = 1024; ks = s - 32; }
      }
      int u = m >> 2, r = m & 3;
      const float* src = W + (size_t)(r*HID + lblk*8 + T*4 + u)*K + ks*32 + grp_*8;
      float4 a = *(const float4*)src;
      float4 c = *(const float4*)(src + 4);
      u32x4 o;
      o.x = pack2(a.x, a.y); o.y = pack2(a.z, a.w);
      o.z = pack2(c.x, c.y); o.w = pack2(c.z, c.w);
      sW[i] = o;
    }
  }

  const int w    = tid >> 6, l = tid & 63;
  const int grp  = l >> 4,  col = l & 15;
  const int b    = w*16 + col;
  const int aoff = l;
  const int boff = grp*64 + b;

  const int unitA = lblk*8 + grp;
  const int unitB = lblk*8 + 4 + grp;
  float bsA[4], bsB[4];
  #pragma unroll
  for (int r = 0; r < 4; ++r){
    if (isL1){
      bsA[r] = bi1[r*HID + unitA] + bh1[r*HID + unitA];
      bsB[r] = bi1[r*HID + unitB] + bh1[r*HID + unitB];
    } else {
      bsA[r] = bi2[r*HID + unitA] + bh2[r*HID + unitA];
      bsB[r] = bi2[r*HID + unitB] + bh2[r*HID + unitB];
    }
  }
  float cA = 0.f, cB = 0.f;
  const u32x4* h04 = (const u32x4*)h0P;
  const u32x4* h14 = (const u32x4*)h1P;
  __syncthreads();                            // weights visible; last barrier

  // counter word (u32 units): cnt + ((t*4 + w)*8 + shard)*32
  if (isL1){
    // ================= LAYER-1 blocks =================
    for (int t = 0; t < TX; ++t){
      f32x4 a00={0,0,0,0}, a01={0,0,0,0}, a10={0,0,0,0}, a11={0,0,0,0};
      // x-part first: cover for own-hop propagation
      {
        const u32x4* Bx = xP + (size_t)t*4096;
        #pragma unroll
        for (int s = 0; s < 16; s += 2){
          u32x4 B0 = Bx[s*256 + boff], B1 = Bx[(s+1)*256 + boff];
          MFMA(a00, sW[(s*2+0)*64 + aoff], B0);
          MFMA(a10, sW[(s*2+1)*64 + aoff], B0);
          MFMA(a01, sW[(s*2+2)*64 + aoff], B1);
          MFMA(a11, sW[(s*2+3)*64 + aoff], B1);
        }
      }
      if (t > 0) pollw(cnt0a + ((t-1)*4 + w)*256);
      {
        const u32x4* Bh = h04 + (size_t)t*SLAB_V4;
        #pragma unroll
        for (int s = 0; s < 32; s += 2){
          u32x4 B0 = Bh[s*256 + boff], B1 = Bh[(s+1)*256 + boff];
          MFMA(a00, sW[((16+s)*2+0)*64 + aoff], B0);
          MFMA(a10, sW[((16+s)*2+1)*64 + aoff], B0);
          MFMA(a01, sW[((17+s)*2+0)*64 + aoff], B1);
          MFMA(a11, sW[((17+s)*2+1)*64 + aoff], B1);
        }
      }
      u32 m0 = cell_h(a00, a01, bsA, cA);
      u32 m1 = cell_h(a10, a11, bsB, cB);
      pub_store(h0P + (size_t)(t+1)*SLAB_U16 + (lblk<<9) + (w<<7), m0, m1);
      pub_signal(cnt0b + ((t*4 + w)*8 + shard)*32,     // L2 consumers first
                 cnt0a + ((t*4 + w)*8 + shard)*32);
    }
  } else {
    // ================= LAYER-2 blocks =================
    pollw(cnt0b + (0*4 + w)*256);             // prologue: h0(1) ready?
    for (int t = 0; t < TX; ++t){
      f32x4 a00={0,0,0,0}, a01={0,0,0,0}, a10={0,0,0,0}, a11={0,0,0,0};
      // h0-part first (poll satisfied last iteration)
      {
        const u32x4* Bh = h04 + (size_t)(t+1)*SLAB_V4;
        #pragma unroll
        for (int s = 0; s < 32; s += 2){
          u32x4 B0 = Bh[s*256 + boff], B1 = Bh[(s+1)*256 + boff];
          MFMA(a00, sW[(s*2+0)*64 + aoff], B0);
          MFMA(a10, sW[(s*2+1)*64 + aoff], B0);
          MFMA(a01, sW[((s+1)*2+0)*64 + aoff], B1);
          MFMA(a11, sW[((s+1)*2+1)*64 + aoff], B1);
        }
      }
      // own-group hop had the whole h0-part to propagate
      if (t > 0) pollw(cnt1 + ((t-1)*4 + w)*256);
      {
        const u32x4* Bh = h14 + (size_t)t*SLAB_V4;
        #pragma unroll
        for (int s = 0; s < 32; s += 2){
          u32x4 B0 = Bh[s*256 + boff], B1 = Bh[(s+1)*256 + boff];
          MFMA(a00, sW[((32+s)*2+0)*64 + aoff], B0);
          MFMA(a10, sW[((32+s)*2+1)*64 + aoff], B0);
          MFMA(a01, sW[((33+s)*2+0)*64 + aoff], B1);
          MFMA(a11, sW[((33+s)*2+1)*64 + aoff], B1);
        }
      }
      u32 m0 = cell_h(a00, a01, bsA, cA);
      u32 m1 = cell_h(a10, a11, bsB, cB);
      pub_store(h1P + (size_t)(t+1)*SLAB_U16 + (lblk<<9) + (w<<7), m0, m1);
      // hide next step's (satisfied) h0 poll under the store drain
      if (t + 1 < TX) pollw(cnt0b + ((t+1)*4 + w)*256);
      pub_signal(cnt1 + ((t*4 + w)*8 + shard)*32, (int*)0);
    }
  }
}

// ---------------------------------------------------------------------------
// MFMA output projection with split-precision W_out (bf16 hi + bf16 lo).
// (unchanged from rounds 5-7)
// ---------------------------------------------------------------------------
__global__ __launch_bounds__(256, 1) void out_gemm(
    const u16* __restrict__ h1P, const float* __restrict__ W_out,
    const float* __restrict__ b_out, float* __restrict__ out)
{
  __shared__ u32x4 sA[8192];                  // 128 KB (A hi/lo chunk; C reuse)
  const int tid = threadIdx.x, l = tid & 63, w = tid >> 6;
  const int grp = l >> 4, col = l & 15;
  const int b   = w*16 + col;
  const int vbase = blockIdx.x * 128;
  const int t0    = blockIdx.y * 4;

  f32x4 acc0[8], acc1[8], acc2[8], acc3[8];
  #pragma unroll
  for (int m = 0; m < 8; ++m){
    acc0[m]=(f32x4){0,0,0,0}; acc1[m]=(f32x4){0,0,0,0};
    acc2[m]=(f32x4){0,0,0,0}; acc3[m]=(f32x4){0,0,0,0};
  }
  const u32x4* h14 = (const u32x4*)h1P;

  for (int kc = 0; kc < 4; ++kc){
    __syncthreads();
    #pragma unroll
    for (int k = 0; k < 16; ++k){
      int j = tid + k*256;
      int lane = j & 63, mt = (j >> 6) & 7, s = j >> 9;
      int v  = vbase + mt*16 + (lane & 15);
      int kk = kc*256 + s*32 + (lane >> 4)*8;
      const float* src = W_out + (size_t)v*HID + kk;
      float4 f0 = *(const float4*)src, f1 = *(const float4*)(src + 4);
      float e[8] = {f0.x,f0.y,f0.z,f0.w,f1.x,f1.y,f1.z,f1.w};
      u16 hi[8]; float lo[8];
      #pragma unroll
      for (int r = 0; r < 8; ++r){ hi[r] = f2bf(e[r]); lo[r] = e[r] - bf2f(hi[r]); }
      u32x4 H, L;
      H.x = (u32)hi[0]|((u32)hi[1]<<16); H.y = (u32)hi[2]|((u32)hi[3]<<16);
      H.z = (u32)hi[4]|((u32)hi[5]<<16); H.w = (u32)hi[6]|((u32)hi[7]<<16);
      L.x = pack2(lo[0],lo[1]); L.y = pack2(lo[2],lo[3]);
      L.z = pack2(lo[4],lo[5]); L.w = pack2(lo[6],lo[7]);
      int base = (s*8 + mt)*128 + lane;
      sA[base]      = H;
      sA[base + 64] = L;
    }
    __syncthreads();

    #pragma unroll
    for (int s = 0; s < 8; ++s){
      int ksl = kc*8 + s;
      int bi  = ksl*256 + grp*64 + b;
      u32x4 B0 = h14[(size_t)(t0+1)*SLAB_V4 + bi];
      u32x4 B1 = h14[(size_t)(t0+2)*SLAB_V4 + bi];
      u32x4 B2 = h14[(size_t)(t0+3)*SLAB_V4 + bi];
      u32x4 B3 = h14[(size_t)(t0+4)*SLAB_V4 + bi];
      #pragma unroll
      for (int mt = 0; mt < 8; ++mt){
        u32x4 Ah = sA[(s*8 + mt)*128 + l];
        u32x4 Al = sA[(s*8 + mt)*128 + 64 + l];
        MFMA(acc0[mt], Ah, B0); MFMA(acc1[mt], Ah, B1);
        MFMA(acc2[mt], Ah, B2); MFMA(acc3[mt], Ah, B3);
        MFMA(acc0[mt], Al, B0); MFMA(acc1[mt], Al, B1);
        MFMA(acc2[mt], Al, B2); MFMA(acc3[mt], Al, B3);
      }
    }
  }

  float* sC = (float*)sA;                     // [64][132] fp32
#define EPILOGUE(ACC, TT)                                                       \
  {                                                                             \
    __syncthreads();                                                            \
    _Pragma("unroll")                                                           \
    for (int mt = 0; mt < 8; ++mt){                                             \
      f32x4 a = ACC[mt];                                                        \
      _Pragma("unroll")                                                         \
      for (int r = 0; r < 4; ++r)                                               \
        sC[b*132 + mt*16 + grp*4 + r] = a[r];                                   \
    }                                                                           \
    __syncthreads();                                                            \
    {                                                                           \
      int bb = tid >> 2, q = tid & 3;                                           \
      const float* cp = sC + bb*132 + q*32;                                     \
      const float* bo = b_out + vbase + q*32;                                   \
      float* op = out + ((size_t)(t0+TT)*BATCH + bb)*VOCAB + vbase + q*32;      \
      _Pragma("unroll")                                                         \
      for (int j = 0; j < 8; ++j){                                              \
        float4 cv = *(const float4*)(cp + j*4);                                 \
        float4 bv = *(const float4*)(bo + j*4);                                 \
        float4 ov = {cv.x+bv.x, cv.y+bv.y, cv.z+bv.z, cv.w+bv.w};               \
        *(float4*)(op + j*4) = ov;                                              \
      }                                                                         \
    }                                                                           \
  }
  EPILOGUE(acc0, 0)
  EPILOGUE(acc1, 1)
  EPILOGUE(acc2, 2)
  EPILOGUE(acc3, 3)
#undef EPILOGUE
}

// ---------------------------------------------------------------------------
extern "C" void kernel_launch(void* const* d_in, const int* in_sizes, int n_in,
                              void* d_out, int out_size, void* d_ws, size_t ws_size,
                              hipStream_t stream)
{
  const int*   x     = (const int*)  d_in[0];
  const float* emb   = (const float*)d_in[1];
  const float* W_ih1 = (const float*)d_in[2];
  const float* W_hh1 = (const float*)d_in[3];
  const float* b_ih1 = (const float*)d_in[4];
  const float* b_hh1 = (const float*)d_in[5];
  const float* W_ih2 = (const float*)d_in[6];
  const float* W_hh2 = (const float*)d_in[7];
  const float* b_ih2 = (const float*)d_in[8];
  const float* b_hh2 = (const float*)d_in[9];
  const float* W_out = (const float*)d_in[10];
  const float* b_out = (const float*)d_in[11];
  float* out = (float*)d_out;

  char* ws = (char*)d_ws;
  int*   cnt0a = (int*)  (ws + OFF_CNT0A);
  int*   cnt0b = (int*)  (ws + OFF_CNT0B);
  int*   cnt1  = (int*)  (ws + OFF_CNT1);
  u16*   h0P   = (u16*)  (ws + OFF_H0);
  u16*   h1P   = (u16*)  (ws + OFF_H1);
  u32x4* xP    = (u32x4*)(ws + OFF_XP);

  hipMemsetAsync(ws, 0, 3145728, stream);              // all counters
  hipMemsetAsync(ws + OFF_H0, 0, 131072, stream);      // h0 slab 0 = zeros
  hipMemsetAsync(ws + OFF_H1, 0, 131072, stream);      // h1 slab 0 = zeros

  embed_pack<<<4096, 256, 0, stream>>>(x, emb, xP);

  lstm_persist<<<256, 256, 0, stream>>>(
      xP, h0P, h1P, W_ih1, W_hh1, W_ih2, W_hh2,
      b_ih1, b_hh1, b_ih2, b_hh2, cnt0a, cnt0b, cnt1);

  dim3 og(VOCAB/128, TX/4);
  out_gemm<<<og, 256, 0, stream>>>(h1P, W_out, b_out, out);
}